// Round 1
// baseline (1824.592 us; speedup 1.0000x reference)
//
#include <hip/hip_runtime.h>
#include <math.h>

#define FIXLEN 30.0f
#define BETA   0.25f

// ---------------- ws layout (floats) ----------------
// [0,64)            : per-block channel-norm partial sums (64 blocks)
// [64,128)          : per-block diff partial sums (64 blocks)
// [128, 128+16384)  : e2[n] = |emb_n|^2
// [16512, +65536)   : minv per (token, part)  (16384*4)
// [82048, +65536)   : mini per (token, part)  (int)
#define NORM_OFF 0
#define DIFF_OFF 64
#define E2_OFF   128
#define MINV_OFF 16512
#define MINI_OFF 82048

// ---------------- K1: per-token channel L2 norms ----------------
__global__ void k_norms(const float* __restrict__ z, float* __restrict__ nrm_part) {
    int t = blockIdx.x * 256 + threadIdx.x;   // grid = 64 blocks
    int b = t >> 10, tl = t & 1023;
    const float* zp = z + (size_t)b * 262144 + tl;
    float s = 0.f;
    #pragma unroll 8
    for (int c = 0; c < 256; ++c) {
        float v = zp[(size_t)c << 10];
        s = fmaf(v, v, s);
    }
    float nrm = sqrtf(s);
    __shared__ float red[256];
    red[threadIdx.x] = nrm;
    __syncthreads();
    for (int off = 128; off > 0; off >>= 1) {
        if (threadIdx.x < off) red[threadIdx.x] += red[threadIdx.x + off];
        __syncthreads();
    }
    if (threadIdx.x == 0) nrm_part[blockIdx.x] = red[0];
}

// ---------------- K2: embedding squared norms ----------------
__global__ void k_e2(const float* __restrict__ emb, float* __restrict__ e2) {
    int w = threadIdx.x >> 6, lane = threadIdx.x & 63;
    int n = blockIdx.x * 4 + w;               // grid = 4096 blocks
    const float4* ep = (const float4*)(emb + (size_t)n * 256);
    float4 v = ep[lane];
    float s = v.x * v.x + v.y * v.y + v.z * v.z + v.w * v.w;
    #pragma unroll
    for (int m = 32; m > 0; m >>= 1) s += __shfl_down(s, m);
    if (lane == 0) e2[n] = s;
}

// ---------------- K3: GEMM + running argmin ----------------
#define TT 128            // tokens per block
#define TE 128            // embeddings per chunk
#define BK 32             // k chunk
#define NPART 4
#define EPP (16384 / NPART)

__launch_bounds__(256, 2)
__global__ void k_argmin(const float* __restrict__ z, const float* __restrict__ emb,
                         const float* __restrict__ nrm_part, const float* __restrict__ e2g,
                         float* __restrict__ minv_out, int* __restrict__ mini_out) {
    __shared__ __align__(16) float As[BK][TT];
    __shared__ __align__(16) float Bs[BK][TE];
    __shared__ float e2s[TE];
    __shared__ float redv[TT][16];
    __shared__ int   redi[TT][16];

    int tokBlk = blockIdx.x >> 2;   // 0..127
    int part   = blockIdx.x & 3;    // 0..3
    int t0  = tokBlk * TT;
    int b   = t0 >> 10;
    int tl0 = t0 & 1023;
    const float* zb = z + (size_t)b * 262144 + tl0;

    // scale factor f = scale/FIXLEN, zs = z * f
    float s = 0.f;
    for (int i = 0; i < 64; ++i) s += nrm_part[i];
    float pre_len = s * (1.0f / 16384.0f);
    float scale = (pre_len >= FIXLEN) ? (FIXLEN / pre_len) : 1.0f;
    float f = scale / FIXLEN;

    int tx = threadIdx.x & 15, ty = threadIdx.x >> 4;

    float minv[8];
    int   mini[8];
    #pragma unroll
    for (int i = 0; i < 8; ++i) { minv[i] = 3.4e38f; mini[i] = 0; }

    for (int ec = 0; ec < EPP; ec += TE) {
        int e0 = part * EPP + ec;
        __syncthreads();                      // protect e2s vs prev epilogue readers
        if (threadIdx.x < TE) e2s[threadIdx.x] = e2g[e0 + threadIdx.x];

        float acc[8][8];
        #pragma unroll
        for (int i = 0; i < 8; ++i)
            #pragma unroll
            for (int j = 0; j < 8; ++j) acc[i][j] = 0.f;

        for (int kc = 0; kc < 256; kc += BK) {
            __syncthreads();
            // stage A: As[kk][tt] = zs[t0+tt][kc+kk], float4 coalesced
            {
                int i4 = threadIdx.x * 4;
                #pragma unroll
                for (int r = 0; r < 4; ++r) {
                    int idx = r * 1024 + i4;          // 0..4095
                    int kk = idx >> 7, tt = idx & 127;
                    float4 v = *(const float4*)(zb + ((size_t)(kc + kk) << 10) + tt);
                    v.x *= f; v.y *= f; v.z *= f; v.w *= f;
                    *(float4*)&As[kk][tt] = v;
                }
            }
            // stage B (transposed): Bs[kk][e] = emb[e0+e][kc+kk]
            {
                int kq = threadIdx.x & 7;             // k-quad 0..7
                int e  = threadIdx.x >> 3;            // 0..31
                #pragma unroll
                for (int r = 0; r < 4; ++r) {
                    int ee = e + r * 32;
                    float4 v = *(const float4*)(emb + (size_t)(e0 + ee) * 256 + kc + kq * 4);
                    Bs[kq * 4 + 0][ee] = v.x;
                    Bs[kq * 4 + 1][ee] = v.y;
                    Bs[kq * 4 + 2][ee] = v.z;
                    Bs[kq * 4 + 3][ee] = v.w;
                }
            }
            __syncthreads();
            #pragma unroll
            for (int kk = 0; kk < BK; ++kk) {
                float a[8], bf[8];
                *(float4*)&a[0]  = *(const float4*)&As[kk][ty * 8];
                *(float4*)&a[4]  = *(const float4*)&As[kk][ty * 8 + 4];
                *(float4*)&bf[0] = *(const float4*)&Bs[kk][tx * 8];
                *(float4*)&bf[4] = *(const float4*)&Bs[kk][tx * 8 + 4];
                #pragma unroll
                for (int i = 0; i < 8; ++i)
                    #pragma unroll
                    for (int j = 0; j < 8; ++j)
                        acc[i][j] = fmaf(a[i], bf[j], acc[i][j]);
            }
        }
        // epilogue: d = |e|^2 - 2*dot ; running min with first-index tie-break
        #pragma unroll
        for (int i = 0; i < 8; ++i) {
            #pragma unroll
            for (int j = 0; j < 8; ++j) {
                int n = e0 + tx * 8 + j;
                float d = e2s[tx * 8 + j] - 2.0f * acc[i][j];
                if (d < minv[i] || (d == minv[i] && n < mini[i])) { minv[i] = d; mini[i] = n; }
            }
        }
    }

    // cross-thread (16 tx) reduction per token
    __syncthreads();
    #pragma unroll
    for (int i = 0; i < 8; ++i) {
        redv[ty * 8 + i][tx] = minv[i];
        redi[ty * 8 + i][tx] = mini[i];
    }
    __syncthreads();
    if (threadIdx.x < TT) {
        int tt = threadIdx.x;
        float bv = redv[tt][0]; int bi = redi[tt][0];
        #pragma unroll
        for (int x = 1; x < 16; ++x) {
            float v = redv[tt][x]; int ii = redi[tt][x];
            if (v < bv || (v == bv && ii < bi)) { bv = v; bi = ii; }
        }
        int t = t0 + tt;
        minv_out[t * 4 + part] = bv;
        mini_out[t * 4 + part] = bi;
    }
}

// ---------------- K4: merge parts, gather z_q, diff partials, idx out ----------------
__global__ void k_out(const float* __restrict__ z, const float* __restrict__ emb,
                      const float* __restrict__ nrm_part,
                      const float* __restrict__ minv, const int* __restrict__ mini,
                      float* __restrict__ out, float* __restrict__ diff_part) {
    int blk = blockIdx.x;                 // 64 blocks
    int b = blk >> 2;
    int tl = ((blk & 3) << 8) + threadIdx.x;
    int t = (b << 10) + tl;

    float bv = minv[t * 4]; int bi = mini[t * 4];
    #pragma unroll
    for (int p = 1; p < 4; ++p) {
        float v = minv[t * 4 + p]; int ii = mini[t * 4 + p];
        if (v < bv || (v == bv && ii < bi)) { bv = v; bi = ii; }
    }
    out[4194305 + t] = (float)bi;

    float s = 0.f;
    for (int i = 0; i < 64; ++i) s += nrm_part[i];
    float pre_len = s * (1.0f / 16384.0f);
    float scale = (pre_len >= FIXLEN) ? (FIXLEN / pre_len) : 1.0f;

    const float* erow = emb + (size_t)bi * 256;
    const float* zrow = z + (size_t)b * 262144 + tl;
    float* orow = out + (size_t)b * 262144 + tl;
    float ds = 0.f;
    #pragma unroll 8
    for (int c = 0; c < 256; ++c) {
        float q  = erow[c] * FIXLEN;
        float zt = zrow[(size_t)c << 10] * scale;
        float dd = q - zt;
        ds = fmaf(dd, dd, ds);
        orow[(size_t)c << 10] = q;
    }
    __shared__ float red[256];
    red[threadIdx.x] = ds;
    __syncthreads();
    for (int off = 128; off > 0; off >>= 1) {
        if (threadIdx.x < off) red[threadIdx.x] += red[threadIdx.x + off];
        __syncthreads();
    }
    if (threadIdx.x == 0) diff_part[blk] = red[0];
}

// ---------------- K5: finalize diff ----------------
__global__ void k_diff(const float* __restrict__ diff_part, float* __restrict__ out) {
    if (threadIdx.x == 0) {
        float s = 0.f;
        for (int i = 0; i < 64; ++i) s += diff_part[i];
        out[4194304] = BETA * s / 4194304.0f;
    }
}

extern "C" void kernel_launch(void* const* d_in, const int* in_sizes, int n_in,
                              void* d_out, int out_size, void* d_ws, size_t ws_size,
                              hipStream_t stream) {
    const float* z   = (const float*)d_in[0];
    const float* emb = (const float*)d_in[1];
    float* out = (float*)d_out;
    float* ws  = (float*)d_ws;

    float* nrm_part = ws + NORM_OFF;
    float* diff_part = ws + DIFF_OFF;
    float* e2   = ws + E2_OFF;
    float* minv = ws + MINV_OFF;
    int*   mini = (int*)(ws + MINI_OFF);

    k_norms<<<64, 256, 0, stream>>>(z, nrm_part);
    k_e2<<<4096, 256, 0, stream>>>(emb, e2);
    k_argmin<<<512, 256, 0, stream>>>(z, emb, nrm_part, e2, minv, mini);
    k_out<<<64, 256, 0, stream>>>(z, emb, nrm_part, minv, mini, out, diff_part);
    k_diff<<<1, 64, 0, stream>>>(diff_part, out);
}

// Round 2
// 547.357 us; speedup vs baseline: 3.3335x; 3.3335x over previous
//
#include <hip/hip_runtime.h>
#include <math.h>

#define FIXLEN 30.0f
#define BETA   0.25f

typedef unsigned short ushort_t;
typedef unsigned int uint_t;
typedef unsigned long long ull_t;

typedef short s16x8 __attribute__((ext_vector_type(8)));
typedef float f32x4 __attribute__((ext_vector_type(4)));

// ---------------- ws layout (bytes) ----------------
// [0, 256)                 nrm_part (64 f)
// [256, 512)               diff_part (64 f)
// [512, 66048)             e2 (16384 f)
// [66048, 16843264)        pv: u64 partials [128 part][16384 token]
// [16843264, +8MB)         zhi plane (16384x256 bf16, swizzled)
// [25231872, +8MB)         zlo
// [33620480, +8MB)         ehi
// [42009088, +8MB)         elo   -> total 50397696 B
#define PV_OFF  66048
#define ZHI_OFF 16843264
#define ZLO_OFF 25231872
#define EHI_OFF 33620480
#define ELO_OFF 42009088

__device__ inline ushort_t f2bf(float x) {
    uint_t b = __float_as_uint(x);
    b += 0x7FFFu + ((b >> 16) & 1u);
    return (ushort_t)(b >> 16);
}
__device__ inline float bf2f(ushort_t h) { return __uint_as_float(((uint_t)h) << 16); }

__device__ inline void gl_lds16(const void* g, void* l) {
    __builtin_amdgcn_global_load_lds(
        (const __attribute__((address_space(1))) unsigned int*)g,
        (__attribute__((address_space(3))) unsigned int*)l, 16, 0, 0);
}

// ---------------- K1: per-token channel L2 norms ----------------
__global__ void k_norms(const float* __restrict__ z, float* __restrict__ nrm_part) {
    int t = blockIdx.x * 256 + threadIdx.x;   // grid = 64
    int b = t >> 10, tl = t & 1023;
    const float* zp = z + (size_t)b * 262144 + tl;
    float s = 0.f;
    #pragma unroll 8
    for (int c = 0; c < 256; ++c) {
        float v = zp[(size_t)c << 10];
        s = fmaf(v, v, s);
    }
    float nrm = sqrtf(s);
    __shared__ float red[256];
    red[threadIdx.x] = nrm;
    __syncthreads();
    for (int off = 128; off > 0; off >>= 1) {
        if (threadIdx.x < off) red[threadIdx.x] += red[threadIdx.x + off];
        __syncthreads();
    }
    if (threadIdx.x == 0) nrm_part[blockIdx.x] = red[0];
}

// ---------------- K2: embedding squared norms ----------------
__global__ void k_e2(const float* __restrict__ emb, float* __restrict__ e2) {
    int w = threadIdx.x >> 6, lane = threadIdx.x & 63;
    int n = blockIdx.x * 4 + w;               // grid = 4096
    const float4* ep = (const float4*)(emb + (size_t)n * 256);
    float4 v = ep[lane];
    float s = v.x * v.x + v.y * v.y + v.z * v.z + v.w * v.w;
    #pragma unroll
    for (int m = 32; m > 0; m >>= 1) s += __shfl_down(s, m);
    if (lane == 0) e2[n] = s;
}

// ---------------- K3: split z -> bf16 hi/lo planes (transpose + scale, swizzled) ----------------
__global__ void k_split_z(const float* __restrict__ z, const float* __restrict__ nrm_part,
                          ushort_t* __restrict__ zh, ushort_t* __restrict__ zl) {
    // grid = 1024: b(16) x ctile(4) x stile(16); tile 64c x 64s
    int bi = blockIdx.x;
    int b = bi >> 6, rest = bi & 63;
    int c0 = (rest >> 4) * 64, s0 = (rest & 15) * 64;

    float s = 0.f;
    for (int i = 0; i < 64; ++i) s += nrm_part[i];
    float pre_len = s * (1.0f / 16384.0f);
    float scale = (pre_len >= FIXLEN) ? (FIXLEN / pre_len) : 1.0f;
    float f = scale / FIXLEN;

    __shared__ float ld[64][65];
    int tid = threadIdx.x;
    #pragma unroll
    for (int p = 0; p < 16; ++p) {
        int idx = p * 256 + tid;
        int cc = idx >> 6, ss = idx & 63;
        ld[cc][ss] = z[(size_t)b * 262144 + (size_t)(c0 + cc) * 1024 + s0 + ss];
    }
    __syncthreads();
    #pragma unroll
    for (int p = 0; p < 16; ++p) {
        int idx = p * 256 + tid;
        int ss2 = idx >> 6, cc2 = idx & 63;
        int t = b * 1024 + s0 + ss2;
        int c = c0 + cc2;
        float v = ld[cc2][ss2] * f;
        ushort_t hi = f2bf(v);
        ushort_t lo = f2bf(v - bf2f(hi));
        int group = c >> 5, q = (c >> 3) & 3, j = c & 7;
        int qs = q ^ ((t >> 1) & 3);
        size_t o = (size_t)t * 256 + (group << 5) + (qs << 3) + j;
        zh[o] = hi;
        zl[o] = lo;
    }
}

// ---------------- K4: split emb -> bf16 hi/lo planes (swizzled) ----------------
__global__ void k_split_e(const float* __restrict__ emb,
                          ushort_t* __restrict__ eh, ushort_t* __restrict__ el) {
    int gidx = blockIdx.x * 256 + threadIdx.x;   // grid = 2048 -> 524288 threads
    int n = gidx >> 5;
    int c8 = (gidx & 31) * 8;
    const float* ep = emb + (size_t)n * 256 + c8;
    float4 v0 = *(const float4*)ep;
    float4 v1 = *(const float4*)(ep + 4);
    float vv[8] = {v0.x, v0.y, v0.z, v0.w, v1.x, v1.y, v1.z, v1.w};
    uint_t hw[4], lw[4];
    #pragma unroll
    for (int k = 0; k < 4; ++k) {
        ushort_t h0 = f2bf(vv[2 * k]),     l0 = f2bf(vv[2 * k] - bf2f(h0));
        ushort_t h1 = f2bf(vv[2 * k + 1]), l1 = f2bf(vv[2 * k + 1] - bf2f(h1));
        hw[k] = (uint_t)h0 | ((uint_t)h1 << 16);
        lw[k] = (uint_t)l0 | ((uint_t)l1 << 16);
    }
    int group = c8 >> 5, q = (c8 >> 3) & 3;
    int qs = q ^ ((n >> 1) & 3);
    size_t o = (size_t)n * 256 + (group << 5) + (qs << 3);
    *(uint4*)&eh[o] = make_uint4(hw[0], hw[1], hw[2], hw[3]);
    *(uint4*)&el[o] = make_uint4(lw[0], lw[1], lw[2], lw[3]);
}

// ---------------- K5: MFMA GEMM + argmin partials ----------------
__launch_bounds__(256, 3)
__global__ void k_mfma(const ushort_t* __restrict__ zh, const ushort_t* __restrict__ zl,
                       const ushort_t* __restrict__ eh, const ushort_t* __restrict__ el,
                       const float* __restrict__ e2g, ull_t* __restrict__ pv) {
    __shared__ __align__(16) ushort_t sAhi[4096];   // [128 m][32 k] bf16, swizzled 16B chunks
    __shared__ __align__(16) ushort_t sAlo[4096];
    __shared__ __align__(16) ushort_t sBhi[4096];
    __shared__ __align__(16) ushort_t sBlo[4096];
    __shared__ float e2s[128];
    __shared__ ull_t tokmin[128];

    int bx = blockIdx.x & 127;          // emb tile
    int by = blockIdx.x >> 7;           // token tile
    int t0 = by * 128, n0 = bx * 128;

    int tid = threadIdx.x;
    int w = tid >> 6, lane = tid & 63;
    int ml = lane & 15, q = lane >> 4;
    int wm0 = (w & 1) * 64, wn0 = (w >> 1) * 64;

    if (tid < 128) e2s[tid] = e2g[n0 + tid];

    // staging role: wave w stages one plane
    const char* gplane;
    ushort_t* lplane;
    if (w == 0)      { gplane = (const char*)zh + (size_t)t0 * 512; lplane = sAhi; }
    else if (w == 1) { gplane = (const char*)zl + (size_t)t0 * 512; lplane = sAlo; }
    else if (w == 2) { gplane = (const char*)eh + (size_t)n0 * 512; lplane = sBhi; }
    else             { gplane = (const char*)el + (size_t)n0 * 512; lplane = sBlo; }
    const char* grow = gplane + (size_t)(lane >> 2) * 512 + (size_t)(lane & 3) * 16;

    f32x4 acc[4][4];
    #pragma unroll
    for (int i = 0; i < 4; ++i)
        #pragma unroll
        for (int j = 0; j < 4; ++j) acc[i][j] = (f32x4){0.f, 0.f, 0.f, 0.f};

    int sw = (ml >> 1) & 3;   // chunk swizzle for this lane's rows

    for (int ks = 0; ks < 8; ++ks) {
        int kc = ks * 32;
        __syncthreads();
        #pragma unroll
        for (int i = 0; i < 8; ++i) {
            gl_lds16(grow + (size_t)i * 16 * 512 + (size_t)kc * 2,
                     (char*)lplane + i * 1024);
        }
        __syncthreads();

        s16x8 Ah[4], Al[4], Bh[4], Bl[4];
        #pragma unroll
        for (int tj = 0; tj < 4; ++tj) {
            int off = (wn0 + tj * 16 + ml) * 32 + ((q ^ sw) << 3);
            Bh[tj] = *(const s16x8*)&sBhi[off];
            Bl[tj] = *(const s16x8*)&sBlo[off];
        }
        #pragma unroll
        for (int ti = 0; ti < 4; ++ti) {
            int off = (wm0 + ti * 16 + ml) * 32 + ((q ^ sw) << 3);
            Ah[ti] = *(const s16x8*)&sAhi[off];
            Al[ti] = *(const s16x8*)&sAlo[off];
        }
        // three passes: hh, hl, lh — 16 independent accs between reuses
        #pragma unroll
        for (int ti = 0; ti < 4; ++ti)
            #pragma unroll
            for (int tj = 0; tj < 4; ++tj)
                acc[ti][tj] = __builtin_amdgcn_mfma_f32_16x16x32_bf16(Ah[ti], Bh[tj], acc[ti][tj], 0, 0, 0);
        #pragma unroll
        for (int ti = 0; ti < 4; ++ti)
            #pragma unroll
            for (int tj = 0; tj < 4; ++tj)
                acc[ti][tj] = __builtin_amdgcn_mfma_f32_16x16x32_bf16(Ah[ti], Bl[tj], acc[ti][tj], 0, 0, 0);
        #pragma unroll
        for (int ti = 0; ti < 4; ++ti)
            #pragma unroll
            for (int tj = 0; tj < 4; ++tj)
                acc[ti][tj] = __builtin_amdgcn_mfma_f32_16x16x32_bf16(Al[ti], Bh[tj], acc[ti][tj], 0, 0, 0);
    }

    // epilogue: d = |e|^2 - 2*dot, packed-u64 running min
    ull_t mybest[4][4];
    #pragma unroll
    for (int ti = 0; ti < 4; ++ti) {
        #pragma unroll
        for (int r = 0; r < 4; ++r) {
            ull_t best = ~0ull;
            #pragma unroll
            for (int tj = 0; tj < 4; ++tj) {
                int nl = wn0 + tj * 16 + ml;
                float d = e2s[nl] - 2.0f * acc[ti][tj][r];
                uint_t b = __float_as_uint(d);
                uint_t key = (b & 0x80000000u) ? ~b : (b | 0x80000000u);
                ull_t u = ((ull_t)key << 32) | (uint_t)(n0 + nl);
                best = (u < best) ? u : best;
            }
            #pragma unroll
            for (int msk = 1; msk < 16; msk <<= 1) {
                ull_t o = __shfl_xor(best, msk);
                best = (o < best) ? o : best;
            }
            mybest[ti][r] = best;
        }
    }
    if (w < 2) {
        if (ml == 0) {
            #pragma unroll
            for (int ti = 0; ti < 4; ++ti)
                #pragma unroll
                for (int r = 0; r < 4; ++r)
                    tokmin[wm0 + ti * 16 + q * 4 + r] = mybest[ti][r];
        }
    }
    __syncthreads();
    if (w >= 2 && ml == 0) {
        #pragma unroll
        for (int ti = 0; ti < 4; ++ti)
            #pragma unroll
            for (int r = 0; r < 4; ++r) {
                int mrow = wm0 + ti * 16 + q * 4 + r;
                ull_t o = tokmin[mrow];
                ull_t u = mybest[ti][r];
                u = (o < u) ? o : u;
                pv[(size_t)bx * 16384 + t0 + mrow] = u;
            }
    }
}

// ---------------- K6: merge parts, gather z_q, diff partials, idx out ----------------
__global__ void k_out(const float* __restrict__ z, const float* __restrict__ emb,
                      const float* __restrict__ nrm_part,
                      const ull_t* __restrict__ pv,
                      float* __restrict__ out, float* __restrict__ diff_part) {
    int blk = blockIdx.x;                 // 64 blocks
    int b = blk >> 2;
    int tl = ((blk & 3) << 8) + threadIdx.x;
    int t = (b << 10) + tl;

    ull_t best = ~0ull;
    for (int p = 0; p < 128; ++p) {
        ull_t u = pv[(size_t)p * 16384 + t];
        best = (u < best) ? u : best;
    }
    int bi = (int)(best & 0xFFFFFFFFull);
    out[4194305 + t] = (float)bi;

    float s = 0.f;
    for (int i = 0; i < 64; ++i) s += nrm_part[i];
    float pre_len = s * (1.0f / 16384.0f);
    float scale = (pre_len >= FIXLEN) ? (FIXLEN / pre_len) : 1.0f;

    const float* erow = emb + (size_t)bi * 256;
    const float* zrow = z + (size_t)b * 262144 + tl;
    float* orow = out + (size_t)b * 262144 + tl;
    float ds = 0.f;
    #pragma unroll 8
    for (int c = 0; c < 256; ++c) {
        float qv = erow[c] * FIXLEN;
        float zt = zrow[(size_t)c << 10] * scale;
        float dd = qv - zt;
        ds = fmaf(dd, dd, ds);
        orow[(size_t)c << 10] = qv;
    }
    __shared__ float red[256];
    red[threadIdx.x] = ds;
    __syncthreads();
    for (int off = 128; off > 0; off >>= 1) {
        if (threadIdx.x < off) red[threadIdx.x] += red[threadIdx.x + off];
        __syncthreads();
    }
    if (threadIdx.x == 0) diff_part[blk] = red[0];
}

// ---------------- K7: finalize diff ----------------
__global__ void k_diff(const float* __restrict__ diff_part, float* __restrict__ out) {
    if (threadIdx.x == 0) {
        float s = 0.f;
        for (int i = 0; i < 64; ++i) s += diff_part[i];
        out[4194304] = BETA * s / 4194304.0f;
    }
}

extern "C" void kernel_launch(void* const* d_in, const int* in_sizes, int n_in,
                              void* d_out, int out_size, void* d_ws, size_t ws_size,
                              hipStream_t stream) {
    const float* z   = (const float*)d_in[0];
    const float* emb = (const float*)d_in[1];
    float* out = (float*)d_out;
    char* wsb = (char*)d_ws;

    float* nrm_part  = (float*)wsb;
    float* diff_part = (float*)(wsb + 256);
    float* e2        = (float*)(wsb + 512);
    ull_t* pv        = (ull_t*)(wsb + PV_OFF);
    ushort_t* zh     = (ushort_t*)(wsb + ZHI_OFF);
    ushort_t* zl     = (ushort_t*)(wsb + ZLO_OFF);
    ushort_t* eh     = (ushort_t*)(wsb + EHI_OFF);
    ushort_t* el     = (ushort_t*)(wsb + ELO_OFF);

    k_norms<<<64, 256, 0, stream>>>(z, nrm_part);
    k_e2<<<4096, 256, 0, stream>>>(emb, e2);
    k_split_z<<<1024, 256, 0, stream>>>(z, nrm_part, zh, zl);
    k_split_e<<<2048, 256, 0, stream>>>(emb, eh, el);
    k_mfma<<<16384, 256, 0, stream>>>(zh, zl, eh, el, e2, pv);
    k_out<<<64, 256, 0, stream>>>(z, emb, nrm_part, pv, out, diff_part);
    k_diff<<<1, 64, 0, stream>>>(diff_part, out);
}

// Round 3
// 493.173 us; speedup vs baseline: 3.6997x; 1.1099x over previous
//
#include <hip/hip_runtime.h>
#include <hip/hip_fp16.h>
#include <math.h>

#define FIXLEN 30.0f
#define BETA   0.25f

typedef unsigned short u16;
typedef unsigned int   u32;
typedef unsigned long long u64;
typedef _Float16 half8 __attribute__((ext_vector_type(8)));
typedef float    f32x4 __attribute__((ext_vector_type(4)));

// ---------------- ws layout (bytes) ----------------
#define NRM_OFF    0         // f[64]
#define NRMMAX_OFF 256       // f[64]
#define CST_OFF    512       // f[8]: 0=f(=scale/30),1=scale,2=EPS2,3=maxNrm
#define DIFF_OFF   1024      // f[256]
#define ZMAX_OFF   2048      // f[1024]
#define EMAXL_OFF  6144      // f[2048]
#define EMAXE_OFF  14336     // f[2048]
#define E2_OFF     22528     // f[16384]
#define BESTN_OFF  88064     // i[16384]
#define PV_OFF     163840    // u64[128*16384]   (16.78 MB)
#define PV2_OFF    16941056  // f[128*16384]     (8.39 MB)
#define ZH_OFF     25329664  // half[16384*256]  (8.39 MB)
#define EH_OFF     33718272  // half[16384*256]  (8.39 MB) -> total 42.1 MB

__device__ inline u32 fkey(float d) {
    u32 b = __float_as_uint(d);
    return (b & 0x80000000u) ? ~b : (b | 0x80000000u);
}
__device__ inline float fdec(u32 k) {
    u32 b = (k & 0x80000000u) ? (k & 0x7FFFFFFFu) : ~k;
    return __uint_as_float(b);
}
__device__ inline void gl_lds16(const void* g, void* l) {
    __builtin_amdgcn_global_load_lds(
        (const __attribute__((address_space(1))) unsigned int*)g,
        (__attribute__((address_space(3))) unsigned int*)l, 16, 0, 0);
}

// ---------------- K1: per-token channel L2 norms (sum + max partials) ----------------
__global__ void k_norms(const float* __restrict__ z, float* __restrict__ nrm_part,
                        float* __restrict__ nrmmax_part) {
    int t = blockIdx.x * 256 + threadIdx.x;   // grid = 64
    int b = t >> 10, tl = t & 1023;
    const float* zp = z + (size_t)b * 262144 + tl;
    float s = 0.f;
    #pragma unroll 8
    for (int c = 0; c < 256; ++c) {
        float v = zp[(size_t)c << 10];
        s = fmaf(v, v, s);
    }
    float nrm = sqrtf(s);
    __shared__ float rs[256], rm[256];
    rs[threadIdx.x] = nrm; rm[threadIdx.x] = nrm;
    __syncthreads();
    for (int off = 128; off > 0; off >>= 1) {
        if (threadIdx.x < off) {
            rs[threadIdx.x] += rs[threadIdx.x + off];
            rm[threadIdx.x] = fmaxf(rm[threadIdx.x], rm[threadIdx.x + off]);
        }
        __syncthreads();
    }
    if (threadIdx.x == 0) { nrm_part[blockIdx.x] = rs[0]; nrmmax_part[blockIdx.x] = rm[0]; }
}

// ---------------- K2: scalar pass 1 (scale, f, maxNrm) ----------------
__global__ void k_scalar1(const float* __restrict__ nrm_part, const float* __restrict__ nrmmax_part,
                          float* __restrict__ cst) {
    int l = threadIdx.x;   // 64 threads
    float s = nrm_part[l], m = nrmmax_part[l];
    #pragma unroll
    for (int off = 32; off > 0; off >>= 1) {
        s += __shfl_down(s, off);
        m = fmaxf(m, __shfl_down(m, off));
    }
    if (l == 0) {
        float pre_len = s * (1.0f / 16384.0f);
        float scale = (pre_len >= FIXLEN) ? (FIXLEN / pre_len) : 1.0f;
        cst[0] = scale / FIXLEN;
        cst[1] = scale;
        cst[3] = m;
    }
}

// ---------------- K3: emb -> fp16 hi plane + e2 + residual-norm maxes ----------------
__global__ void k_split_e(const float* __restrict__ emb, u16* __restrict__ eh,
                          float* __restrict__ e2, float* __restrict__ emaxl,
                          float* __restrict__ emaxe) {
    int gidx = blockIdx.x * 256 + threadIdx.x;   // grid = 2048
    int n = gidx >> 5;
    int c8 = (gidx & 31) * 8;
    const float* ep = emb + (size_t)n * 256 + c8;
    float4 v0 = *(const float4*)ep;
    float4 v1 = *(const float4*)(ep + 4);
    float vv[8] = {v0.x, v0.y, v0.z, v0.w, v1.x, v1.y, v1.z, v1.w};
    u32 pw[4];
    float s2 = 0.f, r2 = 0.f;
    #pragma unroll
    for (int k = 0; k < 4; ++k) {
        __half h0 = __float2half(vv[2 * k]);
        __half h1 = __float2half(vv[2 * k + 1]);
        float r0 = vv[2 * k] - __half2float(h0);
        float r1 = vv[2 * k + 1] - __half2float(h1);
        s2 = fmaf(vv[2 * k], vv[2 * k], s2);
        s2 = fmaf(vv[2 * k + 1], vv[2 * k + 1], s2);
        r2 = fmaf(r0, r0, r2);
        r2 = fmaf(r1, r1, r2);
        pw[k] = (u32)__half_as_ushort(h0) | ((u32)__half_as_ushort(h1) << 16);
    }
    *(uint4*)(eh + (size_t)n * 256 + c8) = make_uint4(pw[0], pw[1], pw[2], pw[3]);
    #pragma unroll
    for (int off = 16; off > 0; off >>= 1) {
        s2 += __shfl_down(s2, off, 32);
        r2 += __shfl_down(r2, off, 32);
    }
    __shared__ float L1[8], L2[8];
    if ((threadIdx.x & 31) == 0) {
        e2[n] = s2;
        L1[threadIdx.x >> 5] = r2;
        L2[threadIdx.x >> 5] = s2;
    }
    __syncthreads();
    if (threadIdx.x == 0) {
        float a = 0.f, bmax = 0.f;
        #pragma unroll
        for (int i = 0; i < 8; ++i) { a = fmaxf(a, L1[i]); bmax = fmaxf(bmax, L2[i]); }
        emaxl[blockIdx.x] = a;
        emaxe[blockIdx.x] = bmax;
    }
}

// ---------------- K4: z -> fp16 hi plane (transpose + scale) + residual max ----------------
__global__ void k_split_z(const float* __restrict__ z, const float* __restrict__ cst,
                          u16* __restrict__ zh, float* __restrict__ zmax_part) {
    int bi = blockIdx.x;                     // grid = 1024
    int b = bi >> 6, rest = bi & 63;
    int c0 = (rest >> 4) * 64, s0 = (rest & 15) * 64;
    float f = cst[0];
    __shared__ float ld[64][65];
    int tid = threadIdx.x;
    #pragma unroll
    for (int p = 0; p < 16; ++p) {
        int idx = p * 256 + tid;
        int cc = idx >> 6, ss = idx & 63;
        ld[cc][ss] = z[(size_t)b * 262144 + (size_t)(c0 + cc) * 1024 + s0 + ss];
    }
    __syncthreads();
    int ss2 = tid >> 2, cq = tid & 3;
    int t = b * 1024 + s0 + ss2;
    float mr = 0.f;
    u32 pk[8];
    #pragma unroll
    for (int k = 0; k < 8; ++k) pk[k] = 0;
    #pragma unroll
    for (int j = 0; j < 16; ++j) {
        float v = ld[cq * 16 + j][ss2] * f;
        __half h = __float2half(v);
        float r = v - __half2float(h);
        mr = fmaxf(mr, fabsf(r));
        pk[j >> 1] |= ((u32)__half_as_ushort(h)) << ((j & 1) * 16);
    }
    u16* dst = zh + (size_t)t * 256 + c0 + cq * 16;
    *(uint4*)dst = make_uint4(pk[0], pk[1], pk[2], pk[3]);
    *(uint4*)(dst + 8) = make_uint4(pk[4], pk[5], pk[6], pk[7]);
    __shared__ float rm[256];
    rm[tid] = mr;
    __syncthreads();
    for (int off = 128; off > 0; off >>= 1) {
        if (tid < off) rm[tid] = fmaxf(rm[tid], rm[tid + off]);
        __syncthreads();
    }
    if (tid == 0) zmax_part[bi] = rm[0];
}

// ---------------- K5: scalar pass 2 -> EPS2 ----------------
__global__ void k_scalar2(const float* __restrict__ emaxl, const float* __restrict__ emaxe,
                          const float* __restrict__ zmax, float* __restrict__ cst) {
    int tid = threadIdx.x;   // 256
    float a = 0.f, bm = 0.f, c = 0.f;
    for (int i = tid; i < 2048; i += 256) { a = fmaxf(a, emaxl[i]); bm = fmaxf(bm, emaxe[i]); }
    for (int i = tid; i < 1024; i += 256) c = fmaxf(c, zmax[i]);
    __shared__ float A[256], B[256], C[256];
    A[tid] = a; B[tid] = bm; C[tid] = c;
    __syncthreads();
    for (int off = 128; off > 0; off >>= 1) {
        if (tid < off) {
            A[tid] = fmaxf(A[tid], A[tid + off]);
            B[tid] = fmaxf(B[tid], B[tid + off]);
            C[tid] = fmaxf(C[tid], C[tid + off]);
        }
        __syncthreads();
    }
    if (tid == 0) {
        float maxEl = sqrtf(A[0]);
        float maxEh = sqrtf(B[0]) + maxEl;
        float maxZl = 16.0f * C[0];            // ||r_t|| <= sqrt(256)*max|r_k|
        float maxZs = cst[3] * cst[0];
        float maxZh = maxZs + maxZl;
        float eps = 2.0f * (maxZh * maxEl + maxZl * maxEh + maxZl * maxEl) + 0.02f;
        cst[2] = 2.0f * eps;
    }
}

// ---------------- K6: fp16 MFMA GEMM + top-2 argmin partials ----------------
__launch_bounds__(256, 4)
__global__ void k_mfma(const u16* __restrict__ zh, const u16* __restrict__ eh,
                       const float* __restrict__ e2g,
                       u64* __restrict__ pv, float* __restrict__ pv2) {
    __shared__ __align__(16) u16 sA[8192];   // 128 rows x 64 k, XOR-by-row 16B-chunk layout
    __shared__ __align__(16) u16 sB[8192];
    __shared__ float e2s[128];
    __shared__ float m1d[128];
    __shared__ int   m1i[128];
    __shared__ float m2d[128];

    int bx = blockIdx.x & 127, by = blockIdx.x >> 7;
    int t0 = by * 128, n0 = bx * 128;
    int tid = threadIdx.x, w = tid >> 6, lane = tid & 63;
    int ml = lane & 15, q = lane >> 4;
    int wm0 = (w & 1) * 64, wn0 = (w >> 1) * 64;
    int x7 = ml & 7;

    if (tid < 128) e2s[tid] = e2g[n0 + tid];

    // staging: waves 0,1 -> A halves; waves 2,3 -> B halves
    int half_ = w & 1;
    const char* gbase;
    char* lbase;
    if (w < 2) { gbase = (const char*)zh + (size_t)(t0 + half_ * 64) * 512; lbase = (char*)sA + half_ * 8192; }
    else       { gbase = (const char*)eh + (size_t)(n0 + half_ * 64) * 512; lbase = (char*)sB + half_ * 8192; }
    // global chunk fetched by this lane = (lane&7) ^ (lane>>3); LDS slot = lane&7 (linear dst)
    const char* grow = gbase + (size_t)(lane >> 3) * 512 + (size_t)((lane & 7) ^ (lane >> 3)) * 16;

    f32x4 acc[4][4];
    #pragma unroll
    for (int i = 0; i < 4; ++i)
        #pragma unroll
        for (int j = 0; j < 4; ++j) acc[i][j] = (f32x4){0.f, 0.f, 0.f, 0.f};

    for (int ks = 0; ks < 4; ++ks) {
        int kc = ks * 64;
        __syncthreads();
        #pragma unroll
        for (int i = 0; i < 8; ++i)
            gl_lds16(grow + (size_t)i * 4096 + (size_t)kc * 2, lbase + i * 1024);
        __syncthreads();

        #pragma unroll
        for (int hk = 0; hk < 2; ++hk) {
            int kk = hk * 32;
            half8 A[4], B[4];
            #pragma unroll
            for (int tj = 0; tj < 4; ++tj) {
                int row = wn0 + tj * 16 + ml;
                int slot = ((kk >> 3) + q) ^ x7;
                B[tj] = *(const half8*)((const char*)sB + row * 128 + slot * 16);
            }
            #pragma unroll
            for (int ti = 0; ti < 4; ++ti) {
                int row = wm0 + ti * 16 + ml;
                int slot = ((kk >> 3) + q) ^ x7;
                A[ti] = *(const half8*)((const char*)sA + row * 128 + slot * 16);
            }
            #pragma unroll
            for (int ti = 0; ti < 4; ++ti)
                #pragma unroll
                for (int tj = 0; tj < 4; ++tj)
                    acc[ti][tj] = __builtin_amdgcn_mfma_f32_16x16x32_f16(A[ti], B[tj], acc[ti][tj], 0, 0, 0);
        }
    }

    // epilogue: per (ti,r) top-2 over this wave's 64 cols, then cross-wave merge
    float rb1[4][4]; int rbi[4][4]; float rb2[4][4];
    #pragma unroll
    for (int ti = 0; ti < 4; ++ti) {
        #pragma unroll
        for (int r = 0; r < 4; ++r) {
            float b1 = 3.4e38f; int i1 = 0x7fffffff; float b2 = 3.4e38f;
            #pragma unroll
            for (int tj = 0; tj < 4; ++tj) {
                int nl = wn0 + tj * 16 + ml;
                float d = e2s[nl] - 2.0f * acc[ti][tj][r];
                int n = n0 + nl;
                if (d < b1 || (d == b1 && n < i1)) { b2 = b1; b1 = d; i1 = n; }
                else b2 = fminf(b2, d);
            }
            #pragma unroll
            for (int m = 1; m < 16; m <<= 1) {
                float o1 = __shfl_xor(b1, m);
                int   oi = __shfl_xor(i1, m);
                float o2 = __shfl_xor(b2, m);
                if (o1 < b1 || (o1 == b1 && oi < i1)) { b2 = fminf(b1, o2); b1 = o1; i1 = oi; }
                else b2 = fminf(b2, o1);
            }
            rb1[ti][r] = b1; rbi[ti][r] = i1; rb2[ti][r] = b2;
        }
    }
    if (w < 2 && ml == 0) {
        #pragma unroll
        for (int ti = 0; ti < 4; ++ti)
            #pragma unroll
            for (int r = 0; r < 4; ++r) {
                int mr = wm0 + ti * 16 + q * 4 + r;
                m1d[mr] = rb1[ti][r]; m1i[mr] = rbi[ti][r]; m2d[mr] = rb2[ti][r];
            }
    }
    __syncthreads();
    if (w >= 2 && ml == 0) {
        #pragma unroll
        for (int ti = 0; ti < 4; ++ti)
            #pragma unroll
            for (int r = 0; r < 4; ++r) {
                int mr = wm0 + ti * 16 + q * 4 + r;
                float a1 = m1d[mr]; int ai = m1i[mr]; float a2 = m2d[mr];
                float b1 = rb1[ti][r]; int bi_ = rbi[ti][r]; float b2 = rb2[ti][r];
                float f1v; int fi; float f2v;
                if (a1 < b1 || (a1 == b1 && ai < bi_)) { f1v = a1; fi = ai; f2v = fminf(a2, b1); }
                else { f1v = b1; fi = bi_; f2v = fminf(b2, a1); }
                int t = t0 + mr;
                pv[(size_t)bx * 16384 + t] = ((u64)fkey(f1v) << 32) | (u32)fi;
                pv2[(size_t)bx * 16384 + t] = f2v;
            }
    }
}

// ---------------- K7: certify or exact-refine, one wave per token ----------------
__global__ void k_refine(const float* __restrict__ z, const float* __restrict__ emb,
                         const float* __restrict__ e2, const u64* __restrict__ pv,
                         const float* __restrict__ pv2, const float* __restrict__ cst,
                         int* __restrict__ bestn) {
    int w = threadIdx.x >> 6, lane = threadIdx.x & 63;
    int t = blockIdx.x * 4 + w;                 // grid = 4096
    u64 u0 = pv[(size_t)lane * 16384 + t];
    u64 u1 = pv[(size_t)(lane + 64) * 16384 + t];
    float f0 = pv2[(size_t)lane * 16384 + t];
    float f1 = pv2[(size_t)(lane + 64) * 16384 + t];
    u64 ub = (u0 < u1) ? u0 : u1;
    #pragma unroll
    for (int m = 1; m < 64; m <<= 1) {
        u64 o = __shfl_xor(ub, m);
        ub = (o < ub) ? o : ub;
    }
    float amin = fdec((u32)(ub >> 32));
    float d0 = fdec((u32)(u0 >> 32));
    float d1 = fdec((u32)(u1 >> 32));
    float c0 = (u0 == ub) ? f0 : d0;
    float c1 = (u1 == ub) ? f1 : d1;
    float sec = fminf(c0, c1);
    #pragma unroll
    for (int m = 1; m < 64; m <<= 1) sec = fminf(sec, __shfl_xor(sec, m));
    float EPS2 = cst[2];
    int bi;
    if (sec > amin + EPS2) {
        bi = (int)(u32)(ub & 0xFFFFFFFFull);
    } else {
        float f = cst[0];
        int b = t >> 10, hw = t & 1023;
        float zr[4];
        #pragma unroll
        for (int i = 0; i < 4; ++i)
            zr[i] = z[(size_t)b * 262144 + (size_t)(lane + 64 * i) * 1024 + hw] * f;
        u64 m0 = __ballot(d0 <= amin + EPS2);
        u64 m1 = __ballot(d1 <= amin + EPS2);
        u64 eb = ~0ull;
        while (m0 | m1) {
            int p;
            if (m0) { p = __ffsll((long long)m0) - 1; m0 &= m0 - 1; }
            else    { p = __ffsll((long long)m1) - 1 + 64; m1 &= m1 - 1; }
            int na = p * 128 + lane, nb = na + 64;
            const float* ea = emb + (size_t)na * 256;
            const float* ebp = emb + (size_t)nb * 256;
            float sa = 0.f, sb = 0.f;
            for (int k = 0; k < 256; ++k) {
                float zk = __shfl(zr[k >> 6], k & 63);
                sa = fmaf(ea[k], zk, sa);
                sb = fmaf(ebp[k], zk, sb);
            }
            float da = e2[na] - 2.0f * sa;
            float db = e2[nb] - 2.0f * sb;
            u64 ka = ((u64)fkey(da) << 32) | (u32)na;
            u64 kb = ((u64)fkey(db) << 32) | (u32)nb;
            u64 kl = (ka < kb) ? ka : kb;
            eb = (kl < eb) ? kl : eb;
        }
        #pragma unroll
        for (int m = 1; m < 64; m <<= 1) {
            u64 o = __shfl_xor(eb, m);
            eb = (o < eb) ? o : eb;
        }
        bi = (int)(u32)(eb & 0xFFFFFFFFull);
    }
    if (lane == 0) bestn[t] = bi;
}

// ---------------- K8: emit z_q, idx, diff partials ----------------
__global__ void k_emit(const float* __restrict__ z, const float* __restrict__ emb,
                       const float* __restrict__ cst, const int* __restrict__ bestn,
                       float* __restrict__ out, float* __restrict__ diff_part) {
    int blk = blockIdx.x;                 // 256
    int cq = blk >> 6, sub = blk & 63;
    int b = sub >> 2;
    int tl = (sub & 3) * 256 + threadIdx.x;
    int t = b * 1024 + tl;
    int bi = bestn[t];
    if (cq == 0) out[4194305 + t] = (float)bi;
    float scale = cst[1];
    const float* er = emb + (size_t)bi * 256 + cq * 64;
    const float* zr = z + (size_t)b * 262144 + (size_t)cq * 65536 + tl;
    float* orow = out + (size_t)b * 262144 + (size_t)cq * 65536 + tl;
    float ds = 0.f;
    #pragma unroll 8
    for (int j = 0; j < 64; ++j) {
        float qv = er[j] * FIXLEN;
        float zt = zr[(size_t)j << 10] * scale;
        float dd = qv - zt;
        ds = fmaf(dd, dd, ds);
        orow[(size_t)j << 10] = qv;
    }
    __shared__ float red[256];
    red[threadIdx.x] = ds;
    __syncthreads();
    for (int off = 128; off > 0; off >>= 1) {
        if (threadIdx.x < off) red[threadIdx.x] += red[threadIdx.x + off];
        __syncthreads();
    }
    if (threadIdx.x == 0) diff_part[blk] = red[0];
}

// ---------------- K9: finalize diff ----------------
__global__ void k_diff(const float* __restrict__ diff_part, float* __restrict__ out) {
    int tid = threadIdx.x;   // 256
    float s = diff_part[tid];
    __shared__ float red[256];
    red[tid] = s;
    __syncthreads();
    for (int off = 128; off > 0; off >>= 1) {
        if (tid < off) red[tid] += red[tid + off];
        __syncthreads();
    }
    if (tid == 0) out[4194304] = BETA * red[0] / 4194304.0f;
}

extern "C" void kernel_launch(void* const* d_in, const int* in_sizes, int n_in,
                              void* d_out, int out_size, void* d_ws, size_t ws_size,
                              hipStream_t stream) {
    const float* z   = (const float*)d_in[0];
    const float* emb = (const float*)d_in[1];
    float* out = (float*)d_out;
    char* wsb = (char*)d_ws;

    float* nrm_part   = (float*)(wsb + NRM_OFF);
    float* nrmmax_part= (float*)(wsb + NRMMAX_OFF);
    float* cst        = (float*)(wsb + CST_OFF);
    float* diff_part  = (float*)(wsb + DIFF_OFF);
    float* zmax_part  = (float*)(wsb + ZMAX_OFF);
    float* emaxl      = (float*)(wsb + EMAXL_OFF);
    float* emaxe      = (float*)(wsb + EMAXE_OFF);
    float* e2         = (float*)(wsb + E2_OFF);
    int*   bestn      = (int*)(wsb + BESTN_OFF);
    u64*   pv         = (u64*)(wsb + PV_OFF);
    float* pv2        = (float*)(wsb + PV2_OFF);
    u16*   zh         = (u16*)(wsb + ZH_OFF);
    u16*   eh         = (u16*)(wsb + EH_OFF);

    k_norms<<<64, 256, 0, stream>>>(z, nrm_part, nrmmax_part);
    k_scalar1<<<1, 64, 0, stream>>>(nrm_part, nrmmax_part, cst);
    k_split_e<<<2048, 256, 0, stream>>>(emb, eh, e2, emaxl, emaxe);
    k_split_z<<<1024, 256, 0, stream>>>(z, cst, zh, zmax_part);
    k_scalar2<<<1, 256, 0, stream>>>(emaxl, emaxe, zmax_part, cst);
    k_mfma<<<16384, 256, 0, stream>>>(zh, eh, e2, pv, pv2);
    k_refine<<<4096, 256, 0, stream>>>(z, emb, e2, pv, pv2, cst, bestn);
    k_emit<<<256, 256, 0, stream>>>(z, emb, cst, bestn, out, diff_part);
    k_diff<<<1, 256, 0, stream>>>(diff_part, out);
}

// Round 4
// 364.198 us; speedup vs baseline: 5.0099x; 1.3541x over previous
//
#include <hip/hip_runtime.h>
#include <hip/hip_fp16.h>
#include <math.h>

#define FIXLEN 30.0f
#define BETA   0.25f

typedef unsigned short u16;
typedef unsigned int   u32;
typedef unsigned long long u64;
typedef _Float16 half8 __attribute__((ext_vector_type(8)));
typedef float    f32x4 __attribute__((ext_vector_type(4)));

// ---------------- ws layout (bytes) ----------------
#define NRM_OFF    0         // f[64]
#define NRMMAX_OFF 256       // f[64]
#define CST_OFF    512       // f[16]: 0=scale,1=inv_s,2=EPS2,3=maxNrm
#define CNT_OFF    576       // i[1]
#define DIFF_OFF   1024      // f[256]
#define ZMAX_OFF   2048      // f[1024]
#define EMAXL_OFF  6144      // f[2048]
#define EMAXE_OFF  14336     // f[2048]
#define E2_OFF     22528     // f[16384]
#define BESTN_OFF  88064     // i[16384]
#define LIST_OFF   153600    // i[16384]
#define PV1_OFF    219136    // u64[8*16384]
#define PVB2_OFF   1267712   // f[8*16384]
#define ZH_OFF     1792000   // half[16384*256]
#define EH_OFF     10180608  // half[16384*256]  -> total 18569216

__device__ inline u32 fkey(float d) {
    u32 b = __float_as_uint(d);
    return (b & 0x80000000u) ? ~b : (b | 0x80000000u);
}
__device__ inline float fdec(u32 k) {
    u32 b = (k & 0x80000000u) ? (k & 0x7FFFFFFFu) : ~k;
    return __uint_as_float(b);
}
__device__ inline void gl_lds16(const void* g, void* l) {
    __builtin_amdgcn_global_load_lds(
        (const __attribute__((address_space(1))) unsigned int*)g,
        (__attribute__((address_space(3))) unsigned int*)l, 16, 0, 0);
}

// ---------------- K1: per-token channel L2 norms (sum + max partials) ----------------
__global__ void k_norms(const float* __restrict__ z, float* __restrict__ nrm_part,
                        float* __restrict__ nrmmax_part) {
    int t = blockIdx.x * 256 + threadIdx.x;   // grid = 64
    int b = t >> 10, tl = t & 1023;
    const float* zp = z + (size_t)b * 262144 + tl;
    float s = 0.f;
    #pragma unroll 8
    for (int c = 0; c < 256; ++c) {
        float v = zp[(size_t)c << 10];
        s = fmaf(v, v, s);
    }
    float nrm = sqrtf(s);
    __shared__ float rs[256], rm[256];
    rs[threadIdx.x] = nrm; rm[threadIdx.x] = nrm;
    __syncthreads();
    for (int off = 128; off > 0; off >>= 1) {
        if (threadIdx.x < off) {
            rs[threadIdx.x] += rs[threadIdx.x + off];
            rm[threadIdx.x] = fmaxf(rm[threadIdx.x], rm[threadIdx.x + off]);
        }
        __syncthreads();
    }
    if (threadIdx.x == 0) { nrm_part[blockIdx.x] = rs[0]; nrmmax_part[blockIdx.x] = rm[0]; }
}

// ---------------- K2: emb -> fp16 plane + e2 + residual-norm maxes ----------------
__global__ void k_split_e(const float* __restrict__ emb, u16* __restrict__ eh,
                          float* __restrict__ e2, float* __restrict__ emaxl,
                          float* __restrict__ emaxe) {
    int gidx = blockIdx.x * 256 + threadIdx.x;   // grid = 2048
    int n = gidx >> 5;
    int c8 = (gidx & 31) * 8;
    const float* ep = emb + (size_t)n * 256 + c8;
    float4 v0 = *(const float4*)ep;
    float4 v1 = *(const float4*)(ep + 4);
    float vv[8] = {v0.x, v0.y, v0.z, v0.w, v1.x, v1.y, v1.z, v1.w};
    u32 pw[4];
    float s2 = 0.f, r2 = 0.f;
    #pragma unroll
    for (int k = 0; k < 4; ++k) {
        __half h0 = __float2half(vv[2 * k]);
        __half h1 = __float2half(vv[2 * k + 1]);
        float r0 = vv[2 * k] - __half2float(h0);
        float r1 = vv[2 * k + 1] - __half2float(h1);
        s2 = fmaf(vv[2 * k], vv[2 * k], s2);
        s2 = fmaf(vv[2 * k + 1], vv[2 * k + 1], s2);
        r2 = fmaf(r0, r0, r2);
        r2 = fmaf(r1, r1, r2);
        pw[k] = (u32)__half_as_ushort(h0) | ((u32)__half_as_ushort(h1) << 16);
    }
    *(uint4*)(eh + (size_t)n * 256 + c8) = make_uint4(pw[0], pw[1], pw[2], pw[3]);
    #pragma unroll
    for (int off = 16; off > 0; off >>= 1) {
        s2 += __shfl_down(s2, off, 32);
        r2 += __shfl_down(r2, off, 32);
    }
    __shared__ float L1[8], L2[8];
    if ((threadIdx.x & 31) == 0) {
        e2[n] = s2;
        L1[threadIdx.x >> 5] = r2;
        L2[threadIdx.x >> 5] = s2;
    }
    __syncthreads();
    if (threadIdx.x == 0) {
        float a = 0.f, bmax = 0.f;
        #pragma unroll
        for (int i = 0; i < 8; ++i) { a = fmaxf(a, L1[i]); bmax = fmaxf(bmax, L2[i]); }
        emaxl[blockIdx.x] = a;
        emaxe[blockIdx.x] = bmax;
    }
}

// ---------------- K3: z -> fp16(z/30) plane (transpose) + per-token residual-sq partial max ----------------
__global__ void k_split_z(const float* __restrict__ z, u16* __restrict__ zh,
                          float* __restrict__ zmax_part) {
    int bi = blockIdx.x;                     // grid = 1024
    int b = bi >> 6, rest = bi & 63;
    int c0 = (rest >> 4) * 64, s0 = (rest & 15) * 64;
    __shared__ float ld[64][65];
    __shared__ float red2[64][4];
    __shared__ float rmax[64];
    int tid = threadIdx.x;
    #pragma unroll
    for (int p = 0; p < 16; ++p) {
        int idx = p * 256 + tid;
        int cc = idx >> 6, ss = idx & 63;
        ld[cc][ss] = z[(size_t)b * 262144 + (size_t)(c0 + cc) * 1024 + s0 + ss];
    }
    __syncthreads();
    int ss2 = tid >> 2, cq = tid & 3;
    int t = b * 1024 + s0 + ss2;
    float r2 = 0.f;
    u32 pk[8];
    #pragma unroll
    for (int k = 0; k < 8; ++k) pk[k] = 0;
    #pragma unroll
    for (int j = 0; j < 16; ++j) {
        float v = ld[cq * 16 + j][ss2] * (1.0f / 30.0f);
        __half h = __float2half(v);
        float r = v - __half2float(h);
        r2 = fmaf(r, r, r2);
        pk[j >> 1] |= ((u32)__half_as_ushort(h)) << ((j & 1) * 16);
    }
    u16* dst = zh + (size_t)t * 256 + c0 + cq * 16;
    *(uint4*)dst = make_uint4(pk[0], pk[1], pk[2], pk[3]);
    *(uint4*)(dst + 8) = make_uint4(pk[4], pk[5], pk[6], pk[7]);
    red2[ss2][cq] = r2;
    __syncthreads();
    if (tid < 64) rmax[tid] = red2[tid][0] + red2[tid][1] + red2[tid][2] + red2[tid][3];
    __syncthreads();
    for (int off = 32; off > 0; off >>= 1) {
        if (tid < off) rmax[tid] = fmaxf(rmax[tid], rmax[tid + off]);
        __syncthreads();
    }
    if (tid == 0) zmax_part[bi] = rmax[0];
}

// ---------------- K4: merged scalar pass: scale + EPS2 + cnt=0 ----------------
__global__ void k_scalars(const float* __restrict__ nrm_part, const float* __restrict__ nrmmax_part,
                          const float* __restrict__ zmax_part, const float* __restrict__ emaxl,
                          const float* __restrict__ emaxe, float* __restrict__ cst,
                          int* __restrict__ cnt) {
    int tid = threadIdx.x;  // 256
    float s = (tid < 64) ? nrm_part[tid] : 0.f;
    float m = (tid < 64) ? nrmmax_part[tid] : 0.f;
    float zm = 0.f, el = 0.f, ee = 0.f;
    for (int i = tid; i < 1024; i += 256) zm = fmaxf(zm, zmax_part[i]);
    for (int i = tid; i < 2048; i += 256) { el = fmaxf(el, emaxl[i]); ee = fmaxf(ee, emaxe[i]); }
    __shared__ float S[256], M[256], Z[256], L[256], E[256];
    S[tid] = s; M[tid] = m; Z[tid] = zm; L[tid] = el; E[tid] = ee;
    __syncthreads();
    for (int off = 128; off > 0; off >>= 1) {
        if (tid < off) {
            S[tid] += S[tid + off];
            M[tid] = fmaxf(M[tid], M[tid + off]);
            Z[tid] = fmaxf(Z[tid], Z[tid + off]);
            L[tid] = fmaxf(L[tid], L[tid + off]);
            E[tid] = fmaxf(E[tid], E[tid + off]);
        }
        __syncthreads();
    }
    if (tid == 0) {
        float pre_len = S[0] * (1.0f / 16384.0f);
        float scale = (pre_len >= FIXLEN) ? (FIXLEN / pre_len) : 1.0f;
        cst[0] = scale;
        cst[1] = 1.0f / scale;
        cst[3] = M[0];
        float maxA  = M[0] * (1.0f / 30.0f);
        float maxEl = sqrtf(L[0]);
        float maxE  = sqrtf(E[0]);
        float maxZl = 2.0f * sqrtf(Z[0]);
        float eps = 2.0f * (maxA * maxEl + maxZl * maxE + maxZl * maxEl) + 0.03f;
        cst[2] = 2.0f * eps;
        cnt[0] = 0;
    }
}

// ---------------- K5: fp16 MFMA GEMM, 128 tok x 2048 emb per block, running top-2 ----------------
__launch_bounds__(256, 2)
__global__ void k_mfma(const u16* __restrict__ zh, const u16* __restrict__ eh,
                       const float* __restrict__ e2g, const float* __restrict__ cst,
                       u64* __restrict__ pv1, float* __restrict__ pvb2) {
    __shared__ __align__(16) u16 sA[32768];   // 128 rows x 256 k, 16B-chunk XOR-swizzled (low 3 bits)
    __shared__ __align__(16) u16 sB[8192];    // 128 rows x 64 k
    __shared__ float m1s[128];
    __shared__ int   mis[128];
    __shared__ float m2s[128];

    int part = blockIdx.x & 7;        // XCD-aligned: one B-slice per XCD L2
    int tokT = blockIdx.x >> 3;       // 0..127
    int t0 = tokT * 128;
    int nbase = part * 2048;
    float inv_s = cst[1];
    int tid = threadIdx.x, w = tid >> 6, lane = tid & 63;
    int ml = lane & 15, q = lane >> 4;
    int wm0 = (w & 1) * 64, wn0 = (w >> 1) * 64;
    int x7 = ml & 7;

    // stage A (chunk-invariant) once: 4096 16B-chunks, 16 per thread, linear LDS dst
    #pragma unroll
    for (int i = 0; i < 16; ++i) {
        int el = i * 256 + tid;
        int row = el >> 5, j = el & 31;
        int jsrc = (j & 24) | ((j & 7) ^ (row & 7));
        gl_lds16(zh + (size_t)(t0 + row) * 256 + jsrc * 8, (char*)sA + el * 16);
    }

    float b1[16], b2[16]; int i1[16];
    #pragma unroll
    for (int k = 0; k < 16; ++k) { b1[k] = 3.4e38f; b2[k] = 3.4e38f; i1[k] = 0; }

    for (int chunk = 0; chunk < 16; ++chunk) {
        int nc = nbase + chunk * 128;
        float et[4];
        #pragma unroll
        for (int tj = 0; tj < 4; ++tj) et[tj] = e2g[nc + wn0 + tj * 16 + ml] * inv_s;

        f32x4 acc[4][4];
        #pragma unroll
        for (int i = 0; i < 4; ++i)
            #pragma unroll
            for (int j = 0; j < 4; ++j) acc[i][j] = (f32x4){0.f, 0.f, 0.f, 0.f};

        for (int ks = 0; ks < 4; ++ks) {
            __syncthreads();
            #pragma unroll
            for (int i = 0; i < 4; ++i) {
                int el = i * 256 + tid;
                int row = el >> 3, j = el & 7;
                int jsrc = j ^ (row & 7);
                gl_lds16(eh + (size_t)(nc + row) * 256 + ks * 64 + jsrc * 8,
                         (char*)sB + el * 16);
            }
            __syncthreads();
            #pragma unroll
            for (int hk = 0; hk < 2; ++hk) {
                int sl = (hk * 4 + q) ^ x7;
                half8 A[4], B[4];
                #pragma unroll
                for (int tj = 0; tj < 4; ++tj)
                    B[tj] = *(const half8*)((const char*)sB + (wn0 + tj * 16 + ml) * 128 + sl * 16);
                #pragma unroll
                for (int ti = 0; ti < 4; ++ti)
                    A[ti] = *(const half8*)((const char*)sA + (wm0 + ti * 16 + ml) * 512 + (ks * 8 + sl) * 16);
                #pragma unroll
                for (int ti = 0; ti < 4; ++ti)
                    #pragma unroll
                    for (int tj = 0; tj < 4; ++tj)
                        acc[ti][tj] = __builtin_amdgcn_mfma_f32_16x16x32_f16(A[ti], B[tj], acc[ti][tj], 0, 0, 0);
            }
        }
        // per-chunk register top-2 update (no cross-lane work)
        #pragma unroll
        for (int ti = 0; ti < 4; ++ti) {
            #pragma unroll
            for (int r = 0; r < 4; ++r) {
                int k = ti * 4 + r;
                #pragma unroll
                for (int tj = 0; tj < 4; ++tj) {
                    float d = fmaf(-2.0f, acc[ti][tj][r], et[tj]);
                    int n = nc + wn0 + tj * 16 + ml;
                    b2[k] = fminf(b2[k], fmaxf(b1[k], d));
                    bool c = d < b1[k];
                    b1[k] = fminf(b1[k], d);
                    i1[k] = c ? n : i1[k];
                }
            }
        }
    }

    // once per block: cross-lane merge over ml (masks 1,2,4,8); ties fall to refine via b2
    #pragma unroll
    for (int k = 0; k < 16; ++k) {
        #pragma unroll
        for (int m = 1; m < 16; m <<= 1) {
            float o1 = __shfl_xor(b1[k], m);
            int   oi = __shfl_xor(i1[k], m);
            float o2 = __shfl_xor(b2[k], m);
            float big = fmaxf(b1[k], o1);
            b2[k] = fminf(fminf(b2[k], o2), big);
            bool c = o1 < b1[k];
            i1[k] = c ? oi : i1[k];
            b1[k] = fminf(b1[k], o1);
        }
    }
    if (w < 2 && ml == 0) {
        #pragma unroll
        for (int ti = 0; ti < 4; ++ti)
            #pragma unroll
            for (int r = 0; r < 4; ++r) {
                int mr = wm0 + ti * 16 + q * 4 + r;
                int k = ti * 4 + r;
                m1s[mr] = b1[k]; mis[mr] = i1[k]; m2s[mr] = b2[k];
            }
    }
    __syncthreads();
    if (w >= 2 && ml == 0) {
        #pragma unroll
        for (int ti = 0; ti < 4; ++ti)
            #pragma unroll
            for (int r = 0; r < 4; ++r) {
                int mr = wm0 + ti * 16 + q * 4 + r;
                int k = ti * 4 + r;
                float a1 = m1s[mr]; int ai = mis[mr]; float a2 = m2s[mr];
                float f1, f2; int fi;
                if (a1 < b1[k]) { f1 = a1; fi = ai; f2 = fminf(a2, b1[k]); }
                else            { f1 = b1[k]; fi = i1[k]; f2 = fminf(b2[k], a1); }
                int t = t0 + mr;
                pv1[(size_t)part * 16384 + t] = ((u64)fkey(f1) << 32) | (u32)fi;
                pvb2[(size_t)part * 16384 + t] = f2;
            }
    }
}

// ---------------- K6: certify per token; build uncertified list ----------------
__global__ void k_refine(const u64* __restrict__ pv1, const float* __restrict__ pvb2,
                         const float* __restrict__ cst, int* __restrict__ bestn,
                         int* __restrict__ list, int* __restrict__ cnt) {
    int t = blockIdx.x * 256 + threadIdx.x;   // grid 64
    float EPS2 = cst[2];
    float amin = 3.4e38f, sec = 3.4e38f; int wi = 0;
    #pragma unroll
    for (int p = 0; p < 8; ++p) {
        u64 u = pv1[(size_t)p * 16384 + t];
        float d1 = fdec((u32)(u >> 32));
        float d2 = pvb2[(size_t)p * 16384 + t];
        if (d1 < amin) { sec = fminf(fminf(sec, amin), d2); amin = d1; wi = (int)(u32)(u & 0xFFFFFFFFull); }
        else sec = fminf(sec, d1);
    }
    bool cert = sec > amin + EPS2;
    if (cert) bestn[t] = wi;
    u64 mask = __ballot(!cert);
    if (mask) {
        int lane = threadIdx.x & 63;
        int leader = __ffsll((long long)mask) - 1;
        int base = 0;
        if (lane == leader) base = atomicAdd(cnt, __popcll(mask));
        base = __shfl(base, leader);
        if (!cert) {
            int rank = __popcll(mask & ((1ull << lane) - 1ull));
            list[base + rank] = t;
        }
    }
}

// ---------------- K7: exact refinement of uncertified tokens, one wave per token ----------------
__global__ void k_refine2(const float* __restrict__ z, const float* __restrict__ emb,
                          const float* __restrict__ e2, const u64* __restrict__ pv1,
                          const float* __restrict__ pvb2, const float* __restrict__ cst,
                          const int* __restrict__ cnt, const int* __restrict__ list,
                          int* __restrict__ bestn) {
    __shared__ float az[4][256];
    int w = threadIdx.x >> 6, lane = threadIdx.x & 63;
    int wid = blockIdx.x * 4 + w;              // grid 64 -> 256 waves
    int C = cnt[0];
    float inv_s = cst[1], EPS2 = cst[2];
    for (int it = wid; it < C; it += 256) {
        int t = list[it];
        int b = t >> 10, hw = t & 1023;
        #pragma unroll
        for (int j = 0; j < 4; ++j)
            az[w][lane + 64 * j] = z[(size_t)b * 262144 + (size_t)(lane + 64 * j) * 1024 + hw] * (1.0f / 30.0f);
        float pb1[8], pb2[8]; int pi1[8];
        float amin = 3.4e38f;
        #pragma unroll
        for (int p = 0; p < 8; ++p) {
            u64 u = pv1[(size_t)p * 16384 + t];
            pb1[p] = fdec((u32)(u >> 32));
            pi1[p] = (int)(u32)(u & 0xFFFFFFFFull);
            pb2[p] = pvb2[(size_t)p * 16384 + t];
            amin = fminf(amin, pb1[p]);
        }
        float thresh = amin + EPS2;
        float bestv = 3.4e38f; int bi = 0x7fffffff;
        for (int p = 0; p < 8; ++p) {
            if (pb2[p] <= thresh) {
                // part may hide candidates beyond its top-2: full exact scan (rare ~0.4%)
                for (int it2 = 0; it2 < 32; ++it2) {
                    int n = p * 2048 + it2 * 64 + lane;
                    const float4* ep = (const float4*)(emb + (size_t)n * 256);
                    float s = 0.f;
                    #pragma unroll 16
                    for (int kk = 0; kk < 64; ++kk) {
                        float4 a4 = *(const float4*)&az[w][kk * 4];
                        float4 e4 = ep[kk];
                        s = fmaf(a4.x, e4.x, s); s = fmaf(a4.y, e4.y, s);
                        s = fmaf(a4.z, e4.z, s); s = fmaf(a4.w, e4.w, s);
                    }
                    float d = fmaf(-2.0f, s, e2[n] * inv_s);
                    if (d < bestv || (d == bestv && n < bi)) { bestv = d; bi = n; }
                }
            } else if (pb1[p] <= thresh) {
                // single candidate: exact distributed dot
                int n = pi1[p];
                float4 a4 = *(const float4*)&az[w][lane * 4];
                float4 e4 = *(const float4*)&emb[(size_t)n * 256 + lane * 4];
                float s = a4.x * e4.x + a4.y * e4.y + a4.z * e4.z + a4.w * e4.w;
                #pragma unroll
                for (int m = 1; m < 64; m <<= 1) s += __shfl_xor(s, m);
                float d = fmaf(-2.0f, s, e2[n] * inv_s);
                if (d < bestv || (d == bestv && n < bi)) { bestv = d; bi = n; }
            }
        }
        #pragma unroll
        for (int m = 1; m < 64; m <<= 1) {
            float ov = __shfl_xor(bestv, m);
            int oi = __shfl_xor(bi, m);
            if (ov < bestv || (ov == bestv && oi < bi)) { bestv = ov; bi = oi; }
        }
        if (lane == 0) bestn[t] = bi;
    }
}

// ---------------- K8: emit z_q, idx, diff partials ----------------
__global__ void k_emit(const float* __restrict__ z, const float* __restrict__ emb,
                       const float* __restrict__ cst, const int* __restrict__ bestn,
                       float* __restrict__ out, float* __restrict__ diff_part) {
    int blk = blockIdx.x;                 // 256
    int cq = blk >> 6, sub = blk & 63;
    int b = sub >> 2;
    int tl = (sub & 3) * 256 + threadIdx.x;
    int t = b * 1024 + tl;
    int bi = bestn[t];
    if (cq == 0) out[4194305 + t] = (float)bi;
    float scale = cst[0];
    const float* er = emb + (size_t)bi * 256 + cq * 64;
    const float* zr = z + (size_t)b * 262144 + (size_t)cq * 65536 + tl;
    float* orow = out + (size_t)b * 262144 + (size_t)cq * 65536 + tl;
    float ds = 0.f;
    #pragma unroll 8
    for (int j = 0; j < 64; ++j) {
        float qv = er[j] * FIXLEN;
        float zt = zr[(size_t)j << 10] * scale;
        float dd = qv - zt;
        ds = fmaf(dd, dd, ds);
        orow[(size_t)j << 10] = qv;
    }
    __shared__ float red[256];
    red[threadIdx.x] = ds;
    __syncthreads();
    for (int off = 128; off > 0; off >>= 1) {
        if (threadIdx.x < off) red[threadIdx.x] += red[threadIdx.x + off];
        __syncthreads();
    }
    if (threadIdx.x == 0) diff_part[blk] = red[0];
}

// ---------------- K9: finalize diff ----------------
__global__ void k_diff(const float* __restrict__ diff_part, float* __restrict__ out) {
    int tid = threadIdx.x;   // 256
    __shared__ float red[256];
    red[tid] = diff_part[tid];
    __syncthreads();
    for (int off = 128; off > 0; off >>= 1) {
        if (tid < off) red[tid] += red[tid + off];
        __syncthreads();
    }
    if (tid == 0) out[4194304] = BETA * red[0] / 4194304.0f;
}

extern "C" void kernel_launch(void* const* d_in, const int* in_sizes, int n_in,
                              void* d_out, int out_size, void* d_ws, size_t ws_size,
                              hipStream_t stream) {
    const float* z   = (const float*)d_in[0];
    const float* emb = (const float*)d_in[1];
    float* out = (float*)d_out;
    char* wsb = (char*)d_ws;

    float* nrm_part    = (float*)(wsb + NRM_OFF);
    float* nrmmax_part = (float*)(wsb + NRMMAX_OFF);
    float* cst         = (float*)(wsb + CST_OFF);
    int*   cnt         = (int*)(wsb + CNT_OFF);
    float* diff_part   = (float*)(wsb + DIFF_OFF);
    float* zmax_part   = (float*)(wsb + ZMAX_OFF);
    float* emaxl       = (float*)(wsb + EMAXL_OFF);
    float* emaxe       = (float*)(wsb + EMAXE_OFF);
    float* e2          = (float*)(wsb + E2_OFF);
    int*   bestn       = (int*)(wsb + BESTN_OFF);
    int*   list        = (int*)(wsb + LIST_OFF);
    u64*   pv1         = (u64*)(wsb + PV1_OFF);
    float* pvb2        = (float*)(wsb + PVB2_OFF);
    u16*   zh          = (u16*)(wsb + ZH_OFF);
    u16*   eh          = (u16*)(wsb + EH_OFF);

    k_norms<<<64, 256, 0, stream>>>(z, nrm_part, nrmmax_part);
    k_split_e<<<2048, 256, 0, stream>>>(emb, eh, e2, emaxl, emaxe);
    k_split_z<<<1024, 256, 0, stream>>>(z, zh, zmax_part);
    k_scalars<<<1, 256, 0, stream>>>(nrm_part, nrmmax_part, zmax_part, emaxl, emaxe, cst, cnt);
    k_mfma<<<1024, 256, 0, stream>>>(zh, eh, e2, cst, pv1, pvb2);
    k_refine<<<64, 256, 0, stream>>>(pv1, pvb2, cst, bestn, list, cnt);
    k_refine2<<<64, 256, 0, stream>>>(z, emb, e2, pv1, pvb2, cst, cnt, list, bestn);
    k_emit<<<256, 256, 0, stream>>>(z, emb, cst, bestn, out, diff_part);
    k_diff<<<1, 256, 0, stream>>>(diff_part, out);
}

// Round 6
// 292.168 us; speedup vs baseline: 6.2450x; 1.2465x over previous
//
#include <hip/hip_runtime.h>
#include <hip/hip_fp16.h>
#include <math.h>

#define FIXLEN 30.0f
#define BETA   0.25f

typedef unsigned short u16;
typedef unsigned int   u32;
typedef unsigned long long u64;
typedef _Float16 half8 __attribute__((ext_vector_type(8)));
typedef float    f32x4 __attribute__((ext_vector_type(4)));

// ---------------- ws layout (bytes) ----------------
#define NRM_OFF    0         // f[64]
#define NRMMAX_OFF 256       // f[64]
#define CST_OFF    512       // f[16]: 0=scale,1=inv_s,2=EPS2,3=maxNrm
#define CNT_OFF    576       // i[1]
#define DIFF_OFF   1024      // f[256]
#define ZMAX_OFF   2048      // f[1024]
#define EMAXL_OFF  6144      // f[2048]
#define EMAXE_OFF  14336     // f[2048]
#define E2_OFF     22528     // f[16384]
#define BESTN_OFF  88064     // i[16384]
#define LIST_OFF   153600    // i[16384]
#define PV1_OFF    219136    // u64[8*16384]
#define PVB2_OFF   1267712   // f[8*16384]
#define ZH_OFF     1792000   // half[16384*256]
#define EH_OFF     10180608  // half[16384*256]  -> total 18569216

__device__ inline u32 fkey(float d) {
    u32 b = __float_as_uint(d);
    return (b & 0x80000000u) ? ~b : (b | 0x80000000u);
}
__device__ inline float fdec(u32 k) {
    u32 b = (k & 0x80000000u) ? (k & 0x7FFFFFFFu) : ~k;
    return __uint_as_float(b);
}
__device__ inline void gl_lds16(const void* g, void* l) {
    __builtin_amdgcn_global_load_lds(
        (const __attribute__((address_space(1))) unsigned int*)g,
        (__attribute__((address_space(3))) unsigned int*)l, 16, 0, 0);
}

// ---------------- K1: per-token channel L2 norms (sum + max partials) ----------------
__global__ void k_norms(const float* __restrict__ z, float* __restrict__ nrm_part,
                        float* __restrict__ nrmmax_part) {
    int t = blockIdx.x * 256 + threadIdx.x;   // grid = 64
    int b = t >> 10, tl = t & 1023;
    const float* zp = z + (size_t)b * 262144 + tl;
    float s = 0.f;
    #pragma unroll 8
    for (int c = 0; c < 256; ++c) {
        float v = zp[(size_t)c << 10];
        s = fmaf(v, v, s);
    }
    float nrm = sqrtf(s);
    __shared__ float rs[256], rm[256];
    rs[threadIdx.x] = nrm; rm[threadIdx.x] = nrm;
    __syncthreads();
    for (int off = 128; off > 0; off >>= 1) {
        if (threadIdx.x < off) {
            rs[threadIdx.x] += rs[threadIdx.x + off];
            rm[threadIdx.x] = fmaxf(rm[threadIdx.x], rm[threadIdx.x + off]);
        }
        __syncthreads();
    }
    if (threadIdx.x == 0) { nrm_part[blockIdx.x] = rs[0]; nrmmax_part[blockIdx.x] = rm[0]; }
}

// ---------------- K2: emb -> fp16 plane + e2 + residual-norm maxes ----------------
__global__ void k_split_e(const float* __restrict__ emb, u16* __restrict__ eh,
                          float* __restrict__ e2, float* __restrict__ emaxl,
                          float* __restrict__ emaxe) {
    int gidx = blockIdx.x * 256 + threadIdx.x;   // grid = 2048
    int n = gidx >> 5;
    int c8 = (gidx & 31) * 8;
    const float* ep = emb + (size_t)n * 256 + c8;
    float4 v0 = *(const float4*)ep;
    float4 v1 = *(const float4*)(ep + 4);
    float vv[8] = {v0.x, v0.y, v0.z, v0.w, v1.x, v1.y, v1.z, v1.w};
    u32 pw[4];
    float s2 = 0.f, r2 = 0.f;
    #pragma unroll
    for (int k = 0; k < 4; ++k) {
        __half h0 = __float2half(vv[2 * k]);
        __half h1 = __float2half(vv[2 * k + 1]);
        float r0 = vv[2 * k] - __half2float(h0);
        float r1 = vv[2 * k + 1] - __half2float(h1);
        s2 = fmaf(vv[2 * k], vv[2 * k], s2);
        s2 = fmaf(vv[2 * k + 1], vv[2 * k + 1], s2);
        r2 = fmaf(r0, r0, r2);
        r2 = fmaf(r1, r1, r2);
        pw[k] = (u32)__half_as_ushort(h0) | ((u32)__half_as_ushort(h1) << 16);
    }
    *(uint4*)(eh + (size_t)n * 256 + c8) = make_uint4(pw[0], pw[1], pw[2], pw[3]);
    #pragma unroll
    for (int off = 16; off > 0; off >>= 1) {
        s2 += __shfl_down(s2, off, 32);
        r2 += __shfl_down(r2, off, 32);
    }
    __shared__ float L1[8], L2[8];
    if ((threadIdx.x & 31) == 0) {
        e2[n] = s2;
        L1[threadIdx.x >> 5] = r2;
        L2[threadIdx.x >> 5] = s2;
    }
    __syncthreads();
    if (threadIdx.x == 0) {
        float a = 0.f, bmax = 0.f;
        #pragma unroll
        for (int i = 0; i < 8; ++i) { a = fmaxf(a, L1[i]); bmax = fmaxf(bmax, L2[i]); }
        emaxl[blockIdx.x] = a;
        emaxe[blockIdx.x] = bmax;
    }
}

// ---------------- K3: z -> fp16(z/30) plane (transpose) + per-token residual-sq partial max ----------------
__global__ void k_split_z(const float* __restrict__ z, u16* __restrict__ zh,
                          float* __restrict__ zmax_part) {
    int bi = blockIdx.x;                     // grid = 1024
    int b = bi >> 6, rest = bi & 63;
    int c0 = (rest >> 4) * 64, s0 = (rest & 15) * 64;
    __shared__ float ld[64][65];
    __shared__ float red2[64][4];
    __shared__ float rmax[64];
    int tid = threadIdx.x;
    #pragma unroll
    for (int p = 0; p < 16; ++p) {
        int idx = p * 256 + tid;
        int cc = idx >> 6, ss = idx & 63;
        ld[cc][ss] = z[(size_t)b * 262144 + (size_t)(c0 + cc) * 1024 + s0 + ss];
    }
    __syncthreads();
    int ss2 = tid >> 2, cq = tid & 3;
    int t = b * 1024 + s0 + ss2;
    float r2 = 0.f;
    u32 pk[8];
    #pragma unroll
    for (int k = 0; k < 8; ++k) pk[k] = 0;
    #pragma unroll
    for (int j = 0; j < 16; ++j) {
        float v = ld[cq * 16 + j][ss2] * (1.0f / 30.0f);
        __half h = __float2half(v);
        float r = v - __half2float(h);
        r2 = fmaf(r, r, r2);
        pk[j >> 1] |= ((u32)__half_as_ushort(h)) << ((j & 1) * 16);
    }
    u16* dst = zh + (size_t)t * 256 + c0 + cq * 16;
    *(uint4*)dst = make_uint4(pk[0], pk[1], pk[2], pk[3]);
    *(uint4*)(dst + 8) = make_uint4(pk[4], pk[5], pk[6], pk[7]);
    red2[ss2][cq] = r2;
    __syncthreads();
    if (tid < 64) rmax[tid] = red2[tid][0] + red2[tid][1] + red2[tid][2] + red2[tid][3];
    __syncthreads();
    for (int off = 32; off > 0; off >>= 1) {
        if (tid < off) rmax[tid] = fmaxf(rmax[tid], rmax[tid + off]);
        __syncthreads();
    }
    if (tid == 0) zmax_part[bi] = rmax[0];
}

// ---------------- K4: merged scalar pass: scale + EPS2 + cnt=0 ----------------
__global__ void k_scalars(const float* __restrict__ nrm_part, const float* __restrict__ nrmmax_part,
                          const float* __restrict__ zmax_part, const float* __restrict__ emaxl,
                          const float* __restrict__ emaxe, float* __restrict__ cst,
                          int* __restrict__ cnt) {
    int tid = threadIdx.x;  // 256
    float s = (tid < 64) ? nrm_part[tid] : 0.f;
    float m = (tid < 64) ? nrmmax_part[tid] : 0.f;
    float zm = 0.f, el = 0.f, ee = 0.f;
    for (int i = tid; i < 1024; i += 256) zm = fmaxf(zm, zmax_part[i]);
    for (int i = tid; i < 2048; i += 256) { el = fmaxf(el, emaxl[i]); ee = fmaxf(ee, emaxe[i]); }
    __shared__ float S[256], M[256], Z[256], L[256], E[256];
    S[tid] = s; M[tid] = m; Z[tid] = zm; L[tid] = el; E[tid] = ee;
    __syncthreads();
    for (int off = 128; off > 0; off >>= 1) {
        if (tid < off) {
            S[tid] += S[tid + off];
            M[tid] = fmaxf(M[tid], M[tid + off]);
            Z[tid] = fmaxf(Z[tid], Z[tid + off]);
            L[tid] = fmaxf(L[tid], L[tid + off]);
            E[tid] = fmaxf(E[tid], E[tid + off]);
        }
        __syncthreads();
    }
    if (tid == 0) {
        float pre_len = S[0] * (1.0f / 16384.0f);
        float scale = (pre_len >= FIXLEN) ? (FIXLEN / pre_len) : 1.0f;
        cst[0] = scale;
        cst[1] = 1.0f / scale;
        cst[3] = M[0];
        float maxA  = M[0] * (1.0f / 30.0f);
        float maxEl = sqrtf(L[0]);
        float maxE  = sqrtf(E[0]);
        float maxZl = 2.0f * sqrtf(Z[0]);
        float eps = 2.0f * (maxA * maxEl + maxZl * maxE + maxZl * maxEl) + 0.03f;
        cst[2] = 2.0f * eps;
        cnt[0] = 0;
    }
}

// ---------------- K5: fp16 MFMA GEMM (round-4 validated core), 128 tok x 2048 emb per block ----------------
// LDS: resident token plane 64 KB @0 + emb k-slice 16 KB @65536 = 81920 B -> 2 blocks/CU (163840 = full pool).
// Merge arrays overlay the dead emb-slice region at the end (extra barrier before overlay).
__launch_bounds__(256, 2)
__global__ void k_mfma(const u16* __restrict__ zh, const u16* __restrict__ eh,
                       const float* __restrict__ e2g, const float* __restrict__ cst,
                       u64* __restrict__ pv1, float* __restrict__ pvb2) {
    __shared__ __align__(16) char lds[81920];
    char* sAb = lds;            // tokens [128 rows][256 k], 16B-chunk XOR swizzle (low 3 bits by row&7)
    char* sBb = lds + 65536;    // emb slice [128 rows][64 k], XOR swizzle

    int part = blockIdx.x & 7;        // XCD-aligned: one B-slice per XCD L2
    int tokT = blockIdx.x >> 3;       // 0..127
    int t0 = tokT * 128;
    int nbase = part * 2048;
    float inv_s = cst[1];
    int tid = threadIdx.x, w = tid >> 6, lane = tid & 63;
    int ml = lane & 15, q = lane >> 4;
    int wm0 = (w & 1) * 64, wn0 = (w >> 1) * 64;
    int x7 = ml & 15 & 7;

    // stage resident token plane: 4096 16B chunks, 16/thread, linear LDS dst, source-XOR swizzle
    #pragma unroll
    for (int i = 0; i < 16; ++i) {
        int el = i * 256 + tid;
        int row = el >> 5, j = el & 31;
        int jsrc = (j & 24) | ((j & 7) ^ (row & 7));
        gl_lds16(zh + (size_t)(t0 + row) * 256 + jsrc * 8, sAb + el * 16);
    }

    float b1[16], b2[16]; int i1[16];
    #pragma unroll
    for (int k = 0; k < 16; ++k) { b1[k] = 3.4e38f; b2[k] = 3.4e38f; i1[k] = 0; }

    for (int chunk = 0; chunk < 16; ++chunk) {
        int nc = nbase + chunk * 128;
        float et[4];
        #pragma unroll
        for (int tj = 0; tj < 4; ++tj) et[tj] = e2g[nc + wn0 + tj * 16 + ml] * inv_s;

        f32x4 acc[4][4];
        #pragma unroll
        for (int i = 0; i < 4; ++i)
            #pragma unroll
            for (int j = 0; j < 4; ++j) acc[i][j] = (f32x4){0.f, 0.f, 0.f, 0.f};

        for (int ks = 0; ks < 4; ++ks) {
            __syncthreads();
            // stage emb slice: 128 rows x 64 k = 1024 chunks, 4/thread
            #pragma unroll
            for (int i = 0; i < 4; ++i) {
                int el = i * 256 + tid;
                int row = el >> 3, j = el & 7;
                int jsrc = j ^ (row & 7);
                gl_lds16(eh + (size_t)(nc + row) * 256 + ks * 64 + jsrc * 8,
                         sBb + el * 16);
            }
            __syncthreads();
            #pragma unroll
            for (int hk = 0; hk < 2; ++hk) {
                int sl = (hk * 4 + q) ^ x7;
                half8 A[4], B[4];
                #pragma unroll
                for (int tj = 0; tj < 4; ++tj)
                    B[tj] = *(const half8*)(sBb + (wn0 + tj * 16 + ml) * 128 + sl * 16);
                #pragma unroll
                for (int ti = 0; ti < 4; ++ti)
                    A[ti] = *(const half8*)(sAb + (wm0 + ti * 16 + ml) * 512 + (ks * 8 + sl) * 16);
                #pragma unroll
                for (int ti = 0; ti < 4; ++ti)
                    #pragma unroll
                    for (int tj = 0; tj < 4; ++tj)
                        acc[ti][tj] = __builtin_amdgcn_mfma_f32_16x16x32_f16(A[ti], B[tj], acc[ti][tj], 0, 0, 0);
            }
        }
        // per-chunk register top-2 update (no cross-lane work)
        #pragma unroll
        for (int ti = 0; ti < 4; ++ti) {
            #pragma unroll
            for (int r = 0; r < 4; ++r) {
                int k = ti * 4 + r;
                #pragma unroll
                for (int tj = 0; tj < 4; ++tj) {
                    float d = fmaf(-2.0f, acc[ti][tj][r], et[tj]);
                    int n = nc + wn0 + tj * 16 + ml;
                    b2[k] = fminf(b2[k], fmaxf(b1[k], d));
                    bool c = d < b1[k];
                    b1[k] = fminf(b1[k], d);
                    i1[k] = c ? n : i1[k];
                }
            }
        }
    }

    // once per block: cross-lane merge over ml (masks 1,2,4,8); ties fall to refine via b2
    #pragma unroll
    for (int k = 0; k < 16; ++k) {
        #pragma unroll
        for (int m = 1; m < 16; m <<= 1) {
            float o1 = __shfl_xor(b1[k], m);
            int   oi = __shfl_xor(i1[k], m);
            float o2 = __shfl_xor(b2[k], m);
            float big = fmaxf(b1[k], o1);
            b2[k] = fminf(fminf(b2[k], o2), big);
            bool c = o1 < b1[k];
            i1[k] = c ? oi : i1[k];
            b1[k] = fminf(b1[k], o1);
        }
    }
    __syncthreads();   // all LDS compute reads done; overlay merge arrays on emb-slice region
    float* m1s = (float*)sBb;            // [128]
    int*   mis = (int*)(sBb + 512);      // [128]
    float* m2s = (float*)(sBb + 1024);   // [128]
    if (w < 2 && ml == 0) {
        #pragma unroll
        for (int ti = 0; ti < 4; ++ti)
            #pragma unroll
            for (int r = 0; r < 4; ++r) {
                int mr = wm0 + ti * 16 + q * 4 + r;
                int k = ti * 4 + r;
                m1s[mr] = b1[k]; mis[mr] = i1[k]; m2s[mr] = b2[k];
            }
    }
    __syncthreads();
    if (w >= 2 && ml == 0) {
        #pragma unroll
        for (int ti = 0; ti < 4; ++ti)
            #pragma unroll
            for (int r = 0; r < 4; ++r) {
                int mr = wm0 + ti * 16 + q * 4 + r;
                int k = ti * 4 + r;
                float a1 = m1s[mr]; int ai = mis[mr]; float a2 = m2s[mr];
                float f1, f2; int fi;
                if (a1 < b1[k]) { f1 = a1; fi = ai; f2 = fminf(a2, b1[k]); }
                else            { f1 = b1[k]; fi = i1[k]; f2 = fminf(b2[k], a1); }
                int t = t0 + mr;
                pv1[(size_t)part * 16384 + t] = ((u64)fkey(f1) << 32) | (u32)fi;
                pvb2[(size_t)part * 16384 + t] = f2;
            }
    }
}

// ---------------- K6: certify per token; build uncertified list ----------------
__global__ void k_refine(const u64* __restrict__ pv1, const float* __restrict__ pvb2,
                         const float* __restrict__ cst, int* __restrict__ bestn,
                         int* __restrict__ list, int* __restrict__ cnt) {
    int t = blockIdx.x * 256 + threadIdx.x;   // grid 64
    float EPS2 = cst[2];
    float amin = 3.4e38f, sec = 3.4e38f; int wi = 0;
    #pragma unroll
    for (int p = 0; p < 8; ++p) {
        u64 u = pv1[(size_t)p * 16384 + t];
        float d1 = fdec((u32)(u >> 32));
        float d2 = pvb2[(size_t)p * 16384 + t];
        if (d1 < amin) { sec = fminf(fminf(sec, amin), d2); amin = d1; wi = (int)(u32)(u & 0xFFFFFFFFull); }
        else sec = fminf(sec, d1);
    }
    bool cert = sec > amin + EPS2;
    if (cert) bestn[t] = wi;
    u64 mask = __ballot(!cert);
    if (mask) {
        int lane = threadIdx.x & 63;
        int leader = __ffsll((long long)mask) - 1;
        int base = 0;
        if (lane == leader) base = atomicAdd(cnt, __popcll(mask));
        base = __shfl(base, leader);
        if (!cert) {
            int rank = __popcll(mask & ((1ull << lane) - 1ull));
            list[base + rank] = t;
        }
    }
}

// ---------------- K7: exact refinement of uncertified tokens, one wave per token ----------------
__global__ void k_refine2(const float* __restrict__ z, const float* __restrict__ emb,
                          const float* __restrict__ e2, const u64* __restrict__ pv1,
                          const float* __restrict__ pvb2, const float* __restrict__ cst,
                          const int* __restrict__ cnt, const int* __restrict__ list,
                          int* __restrict__ bestn) {
    __shared__ float az[4][256];
    int w = threadIdx.x >> 6, lane = threadIdx.x & 63;
    int wid = blockIdx.x * 4 + w;              // grid 64 -> 256 waves
    int C = cnt[0];
    float inv_s = cst[1], EPS2 = cst[2];
    for (int it = wid; it < C; it += 256) {
        int t = list[it];
        int b = t >> 10, hw = t & 1023;
        #pragma unroll
        for (int j = 0; j < 4; ++j)
            az[w][lane + 64 * j] = z[(size_t)b * 262144 + (size_t)(lane + 64 * j) * 1024 + hw] * (1.0f / 30.0f);
        float pb1[8], pb2[8]; int pi1[8];
        float amin = 3.4e38f;
        #pragma unroll
        for (int p = 0; p < 8; ++p) {
            u64 u = pv1[(size_t)p * 16384 + t];
            pb1[p] = fdec((u32)(u >> 32));
            pi1[p] = (int)(u32)(u & 0xFFFFFFFFull);
            pb2[p] = pvb2[(size_t)p * 16384 + t];
            amin = fminf(amin, pb1[p]);
        }
        float thresh = amin + EPS2;
        float bestv = 3.4e38f; int bi = 0x7fffffff;
        for (int p = 0; p < 8; ++p) {
            if (pb2[p] <= thresh) {
                for (int it2 = 0; it2 < 32; ++it2) {
                    int n = p * 2048 + it2 * 64 + lane;
                    const float4* ep = (const float4*)(emb + (size_t)n * 256);
                    float s = 0.f;
                    #pragma unroll 16
                    for (int kk = 0; kk < 64; ++kk) {
                        float4 a4 = *(const float4*)&az[w][kk * 4];
                        float4 e4 = ep[kk];
                        s = fmaf(a4.x, e4.x, s); s = fmaf(a4.y, e4.y, s);
                        s = fmaf(a4.z, e4.z, s); s = fmaf(a4.w, e4.w, s);
                    }
                    float d = fmaf(-2.0f, s, e2[n] * inv_s);
                    if (d < bestv || (d == bestv && n < bi)) { bestv = d; bi = n; }
                }
            } else if (pb1[p] <= thresh) {
                int n = pi1[p];
                float4 a4 = *(const float4*)&az[w][lane * 4];
                float4 e4 = *(const float4*)&emb[(size_t)n * 256 + lane * 4];
                float s = a4.x * e4.x + a4.y * e4.y + a4.z * e4.z + a4.w * e4.w;
                #pragma unroll
                for (int m = 1; m < 64; m <<= 1) s += __shfl_xor(s, m);
                float d = fmaf(-2.0f, s, e2[n] * inv_s);
                if (d < bestv || (d == bestv && n < bi)) { bestv = d; bi = n; }
            }
        }
        #pragma unroll
        for (int m = 1; m < 64; m <<= 1) {
            float ov = __shfl_xor(bestv, m);
            int oi = __shfl_xor(bi, m);
            if (ov < bestv || (ov == bestv && oi < bi)) { bestv = ov; bi = oi; }
        }
        if (lane == 0) bestn[t] = bi;
    }
}

// ---------------- K8: emit z_q, idx, diff partials ----------------
__global__ void k_emit(const float* __restrict__ z, const float* __restrict__ emb,
                       const float* __restrict__ cst, const int* __restrict__ bestn,
                       float* __restrict__ out, float* __restrict__ diff_part) {
    int blk = blockIdx.x;                 // 256
    int cq = blk >> 6, sub = blk & 63;
    int b = sub >> 2;
    int tl = (sub & 3) * 256 + threadIdx.x;
    int t = b * 1024 + tl;
    int bi = bestn[t];
    if (cq == 0) out[4194305 + t] = (float)bi;
    float scale = cst[0];
    const float* er = emb + (size_t)bi * 256 + cq * 64;
    const float* zr = z + (size_t)b * 262144 + (size_t)cq * 65536 + tl;
    float* orow = out + (size_t)b * 262144 + (size_t)cq * 65536 + tl;
    float ds = 0.f;
    #pragma unroll 8
    for (int j = 0; j < 64; ++j) {
        float qv = er[j] * FIXLEN;
        float zt = zr[(size_t)j << 10] * scale;
        float dd = qv - zt;
        ds = fmaf(dd, dd, ds);
        orow[(size_t)j << 10] = qv;
    }
    __shared__ float red[256];
    red[threadIdx.x] = ds;
    __syncthreads();
    for (int off = 128; off > 0; off >>= 1) {
        if (threadIdx.x < off) red[threadIdx.x] += red[threadIdx.x + off];
        __syncthreads();
    }
    if (threadIdx.x == 0) diff_part[blk] = red[0];
}

// ---------------- K9: finalize diff ----------------
__global__ void k_diff(const float* __restrict__ diff_part, float* __restrict__ out) {
    int tid = threadIdx.x;   // 256
    __shared__ float red[256];
    red[tid] = diff_part[tid];
    __syncthreads();
    for (int off = 128; off > 0; off >>= 1) {
        if (tid < off) red[tid] += red[tid + off];
        __syncthreads();
    }
    if (tid == 0) out[4194304] = BETA * red[0] / 4194304.0f;
}

extern "C" void kernel_launch(void* const* d_in, const int* in_sizes, int n_in,
                              void* d_out, int out_size, void* d_ws, size_t ws_size,
                              hipStream_t stream) {
    const float* z   = (const float*)d_in[0];
    const float* emb = (const float*)d_in[1];
    float* out = (float*)d_out;
    char* wsb = (char*)d_ws;

    float* nrm_part    = (float*)(wsb + NRM_OFF);
    float* nrmmax_part = (float*)(wsb + NRMMAX_OFF);
    float* cst         = (float*)(wsb + CST_OFF);
    int*   cnt         = (int*)(wsb + CNT_OFF);
    float* diff_part   = (float*)(wsb + DIFF_OFF);
    float* zmax_part   = (float*)(wsb + ZMAX_OFF);
    float* emaxl       = (float*)(wsb + EMAXL_OFF);
    float* emaxe       = (float*)(wsb + EMAXE_OFF);
    float* e2          = (float*)(wsb + E2_OFF);
    int*   bestn       = (int*)(wsb + BESTN_OFF);
    int*   list        = (int*)(wsb + LIST_OFF);
    u64*   pv1         = (u64*)(wsb + PV1_OFF);
    float* pvb2        = (float*)(wsb + PVB2_OFF);
    u16*   zh          = (u16*)(wsb + ZH_OFF);
    u16*   eh          = (u16*)(wsb + EH_OFF);

    k_norms<<<64, 256, 0, stream>>>(z, nrm_part, nrmmax_part);
    k_split_e<<<2048, 256, 0, stream>>>(emb, eh, e2, emaxl, emaxe);
    k_split_z<<<1024, 256, 0, stream>>>(z, zh, zmax_part);
    k_scalars<<<1, 256, 0, stream>>>(nrm_part, nrmmax_part, zmax_part, emaxl, emaxe, cst, cnt);
    k_mfma<<<1024, 256, 0, stream>>>(zh, eh, e2, cst, pv1, pvb2);
    k_refine<<<64, 256, 0, stream>>>(pv1, pvb2, cst, bestn, list, cnt);
    k_refine2<<<64, 256, 0, stream>>>(z, emb, e2, pv1, pvb2, cst, cnt, list, bestn);
    k_emit<<<256, 256, 0, stream>>>(z, emb, cst, bestn, out, diff_part);
    k_diff<<<1, 256, 0, stream>>>(diff_part, out);
}